// Round 1
// baseline (978.536 us; speedup 1.0000x reference)
//
#include <hip/hip_runtime.h>
#include <math.h>

#define NEG_SLOPE 0.2f
#define BN_EPS 1e-5f

__device__ __forceinline__ float wave_max64(float v) {
  #pragma unroll
  for (int o = 32; o; o >>= 1) v = fmaxf(v, __shfl_xor(v, o, 64));
  return v;
}
__device__ __forceinline__ float wave_sum64(float v) {
  #pragma unroll
  for (int o = 32; o; o >>= 1) v += __shfl_xor(v, o, 64);
  return v;
}

// ---------------------------------------------------------------------------
// GEMM (K=128): out[r][cb*64+c] = sum_k X[r][k] * W[k][cb*64+c]
// MODE 0: layer-1 feature GEMM -> also computes per-head alpha_s/alpha_d
// MODE 1: skip projection -> adds bias
// Block 256 threads, tile = 64 rows x 64 cols (grid.y = col block 0/1).
// LDS: W half (32KB) + transposed/XOR-swizzled X tile (32KB) = 64KB.
// ---------------------------------------------------------------------------
template<int MODE>
__global__ __launch_bounds__(256) void gemm128_kernel(
    const float* __restrict__ X, const float* __restrict__ W,
    const float* __restrict__ bias,
    const float* __restrict__ att_s, const float* __restrict__ att_d,
    float* __restrict__ out, float* __restrict__ alpha_s, float* __restrict__ alpha_d,
    int nrows)
{
  __shared__ float Wl[128][64];
  __shared__ float Xt[128][64];   // Xt[k][swz(r)] = X[row0+r][k]
  const int t = threadIdx.x;
  const int cb = blockIdx.y;
  const int row0 = blockIdx.x * 64;

  // stage W columns [cb*64, cb*64+64)
  #pragma unroll
  for (int j = 0; j < 8; ++j) {
    int i4 = j * 256 + t;
    int k = i4 >> 4, c = (i4 & 15) * 4;
    float4 w = *(const float4*)(W + (size_t)k * 128 + cb * 64 + c);
    *(float4*)&Wl[k][c] = w;
  }
  // stage X tile transposed; XOR-swizzle column by (k>>2)&31 for bank-conflict-free
  // writes AND reads
  #pragma unroll
  for (int j = 0; j < 8; ++j) {
    int i4 = j * 256 + t;
    int rl = i4 >> 5, kk = (i4 & 31) * 4;
    int r = row0 + rl;
    float4 v = make_float4(0.f, 0.f, 0.f, 0.f);
    if (r < nrows) v = *(const float4*)(X + (size_t)r * 128 + kk);
    int sw = (kk >> 2) & 31;
    int col = (rl & 32) | ((rl & 31) ^ sw);
    Xt[kk + 0][col] = v.x;
    Xt[kk + 1][col] = v.y;
    Xt[kk + 2][col] = v.z;
    Xt[kk + 3][col] = v.w;
  }
  __syncthreads();

  const int cg = t >> 5;        // 0..7 (half-wave uniform)
  const int c0 = cg * 8;
  const int rA = t & 31;        // rows rA and rA+32
  float accA[8] = {0.f, 0.f, 0.f, 0.f, 0.f, 0.f, 0.f, 0.f};
  float accB[8] = {0.f, 0.f, 0.f, 0.f, 0.f, 0.f, 0.f, 0.f};

  #pragma unroll 8
  for (int k = 0; k < 128; ++k) {
    int sw = (k >> 2) & 31;
    float xa = Xt[k][rA ^ sw];
    float xb = Xt[k][32 | (rA ^ sw)];
    float4 w0 = *(float4*)&Wl[k][c0];
    float4 w1 = *(float4*)&Wl[k][c0 + 4];
    accA[0] += xa * w0.x; accA[1] += xa * w0.y; accA[2] += xa * w0.z; accA[3] += xa * w0.w;
    accA[4] += xa * w1.x; accA[5] += xa * w1.y; accA[6] += xa * w1.z; accA[7] += xa * w1.w;
    accB[0] += xb * w0.x; accB[1] += xb * w0.y; accB[2] += xb * w0.z; accB[3] += xb * w0.w;
    accB[4] += xb * w1.x; accB[5] += xb * w1.y; accB[6] += xb * w1.z; accB[7] += xb * w1.w;
  }

  const int gc = cb * 64 + c0;
  const int rGA = row0 + rA, rGB = row0 + rA + 32;

  if (MODE == 1) {
    float b[8];
    #pragma unroll
    for (int j = 0; j < 8; ++j) b[j] = bias[gc + j];
    if (rGA < nrows) {
      float* o = out + (size_t)rGA * 128 + gc;
      float4 v0 = make_float4(accA[0] + b[0], accA[1] + b[1], accA[2] + b[2], accA[3] + b[3]);
      float4 v1 = make_float4(accA[4] + b[4], accA[5] + b[5], accA[6] + b[6], accA[7] + b[7]);
      *(float4*)o = v0; *(float4*)(o + 4) = v1;
    }
    if (rGB < nrows) {
      float* o = out + (size_t)rGB * 128 + gc;
      float4 v0 = make_float4(accB[0] + b[0], accB[1] + b[1], accB[2] + b[2], accB[3] + b[3]);
      float4 v1 = make_float4(accB[4] + b[4], accB[5] + b[5], accB[6] + b[6], accB[7] + b[7]);
      *(float4*)o = v0; *(float4*)(o + 4) = v1;
    }
  } else {
    if (rGA < nrows) {
      float* o = out + (size_t)rGA * 128 + gc;
      *(float4*)o = make_float4(accA[0], accA[1], accA[2], accA[3]);
      *(float4*)(o + 4) = make_float4(accA[4], accA[5], accA[6], accA[7]);
    }
    if (rGB < nrows) {
      float* o = out + (size_t)rGB * 128 + gc;
      *(float4*)o = make_float4(accB[0], accB[1], accB[2], accB[3]);
      *(float4*)(o + 4) = make_float4(accB[4], accB[5], accB[6], accB[7]);
    }
    // per-head alpha: this thread's 8 cols are one half of head hh
    const int w = t >> 6;          // wave id 0..3
    const int hh = cb * 4 + w;     // head index
    const int half = (t >> 5) & 1; // which half of the head's 16 channels
    float psA = 0.f, pdA = 0.f, psB = 0.f, pdB = 0.f;
    #pragma unroll
    for (int j = 0; j < 8; ++j) {
      float as_ = att_s[hh * 16 + half * 8 + j];
      float ad_ = att_d[hh * 16 + half * 8 + j];
      psA += accA[j] * as_; pdA += accA[j] * ad_;
      psB += accB[j] * as_; pdB += accB[j] * ad_;
    }
    psA += __shfl_xor(psA, 32, 64); pdA += __shfl_xor(pdA, 32, 64);
    psB += __shfl_xor(psB, 32, 64); pdB += __shfl_xor(pdB, 32, 64);
    if (half == 0) {
      if (rGA < nrows) { alpha_s[(size_t)rGA * 8 + hh] = psA; alpha_d[(size_t)rGA * 8 + hh] = pdA; }
      if (rGB < nrows) { alpha_s[(size_t)rGB * 8 + hh] = psB; alpha_d[(size_t)rGB * 8 + hh] = pdB; }
    }
  }
}

// ---------------------------------------------------------------------------
// CSR-by-dst construction: histogram -> scan -> scatter
// ---------------------------------------------------------------------------
__global__ void count_kernel(const int* __restrict__ dst, int* __restrict__ counts,
                             int E, int T) {
  int i = blockIdx.x * 256 + threadIdx.x;
  if (i < T) {
    int d = (i < E) ? dst[i] : (i - E);   // self-loops appended
    atomicAdd(&counts[d], 1);
  }
}

__global__ void scan1_kernel(const int* __restrict__ counts, int* __restrict__ bsums, int N) {
  __shared__ int red[256];
  int t = threadIdx.x, b = blockIdx.x;
  int base = b * 1024 + t * 4;
  int s = 0;
  #pragma unroll
  for (int j = 0; j < 4; ++j) { int i = base + j; if (i < N) s += counts[i]; }
  red[t] = s; __syncthreads();
  for (int d = 128; d; d >>= 1) {
    if (t < d) red[t] += red[t + d];
    __syncthreads();
  }
  if (t == 0) bsums[b] = red[0];
}

__global__ void scan2_kernel(int* bsums, int nb) {
  if (threadIdx.x == 0) {
    int run = 0;
    for (int i = 0; i < nb; ++i) { int v = bsums[i]; bsums[i] = run; run += v; }
  }
}

__global__ void scan3_kernel(const int* __restrict__ counts, const int* __restrict__ bsums,
                             int* __restrict__ offs, int* __restrict__ cursor, int N, int total) {
  __shared__ int red[256];
  int t = threadIdx.x, b = blockIdx.x;
  int base = b * 1024 + t * 4;
  int loc[4]; int s = 0;
  #pragma unroll
  for (int j = 0; j < 4; ++j) { int i = base + j; loc[j] = (i < N) ? counts[i] : 0; s += loc[j]; }
  red[t] = s;
  __syncthreads();
  for (int d = 1; d < 256; d <<= 1) {
    int v = (t >= d) ? red[t - d] : 0;
    __syncthreads();
    red[t] += v;
    __syncthreads();
  }
  int excl = red[t] - s + bsums[b];
  #pragma unroll
  for (int j = 0; j < 4; ++j) {
    int i = base + j;
    if (i < N) {
      offs[i] = excl; cursor[i] = excl; excl += loc[j];
      if (i == N - 1) offs[N] = total;
    }
  }
}

__global__ void scatter_kernel(const int* __restrict__ src, const int* __restrict__ dst,
                               int* __restrict__ cursor, int* __restrict__ ssrc, int E, int T) {
  int i = blockIdx.x * 256 + threadIdx.x;
  if (i < T) {
    int s, d;
    if (i < E) { s = src[i]; d = dst[i]; } else { s = d = i - E; }
    int pos = atomicAdd(&cursor[d], 1);
    ssrc[pos] = s;
  }
}

// ---------------------------------------------------------------------------
// Layer-1 aggregation: one wave per dst node. lane l -> channels 2l,2l+1,
// head h = l>>3. Two passes over the segment (max, then exp/sum/accumulate).
// Epilogue fuses +bias1, BN(eval), ELU, +identity; writes h_post in place
// over the identity buffer.
// ---------------------------------------------------------------------------
__global__ __launch_bounds__(256) void agg1_kernel(
    const int* __restrict__ offs, const int* __restrict__ ssrc,
    const float* __restrict__ as1, const float* __restrict__ ad1,
    const float* __restrict__ h1,
    const float* __restrict__ bias1, const float* __restrict__ gamma,
    const float* __restrict__ beta, const float* __restrict__ mean,
    const float* __restrict__ var,
    float* __restrict__ hpost, int N)
{
  const int w = threadIdx.x >> 6, l = threadIdx.x & 63;
  const int n = blockIdx.x * 4 + w;
  if (n >= N) return;
  const int h = l >> 3;
  const int c0 = l * 2;
  const float ad = ad1[(size_t)n * 8 + h];
  const int jb = offs[n], je = offs[n + 1];

  float m = -3.4e38f;
  for (int j = jb; j < je; ++j) {
    int s = ssrc[j];
    float e = as1[(size_t)s * 8 + h] + ad;
    e = e > 0.f ? e : NEG_SLOPE * e;
    m = fmaxf(m, e);
  }
  float denom = 0.f, a0 = 0.f, a1 = 0.f;
  for (int j = jb; j < je; ++j) {
    int s = ssrc[j];
    float e = as1[(size_t)s * 8 + h] + ad;
    e = e > 0.f ? e : NEG_SLOPE * e;
    float ex = __expf(e - m);
    denom += ex;
    float2 hv = *(const float2*)(h1 + (size_t)s * 128 + c0);
    a0 += ex * hv.x; a1 += ex * hv.y;
  }
  float inv = 1.f / (denom + 1e-16f);
  float2 idv = *(const float2*)(hpost + (size_t)n * 128 + c0);
  float o0 = a0 * inv + bias1[c0];
  float o1 = a1 * inv + bias1[c0 + 1];
  o0 = (o0 - mean[c0]) * (gamma[c0] * rsqrtf(var[c0] + BN_EPS)) + beta[c0];
  o1 = (o1 - mean[c0 + 1]) * (gamma[c0 + 1] * rsqrtf(var[c0 + 1] + BN_EPS)) + beta[c0 + 1];
  o0 = o0 > 0.f ? o0 : expm1f(o0);
  o1 = o1 > 0.f ? o1 : expm1f(o1);
  o0 += idv.x; o1 += idv.y;
  *(float2*)(hpost + (size_t)n * 128 + c0) = make_float2(o0, o1);
}

// ---------------------------------------------------------------------------
// GEMM2: h2[N,40] = h_post @ W2; also alpha_s2/alpha_d2 (heads=1) via wave
// reduction. One wave per row (lanes 0..39 own output channels).
// ---------------------------------------------------------------------------
__global__ __launch_bounds__(256) void gemm2_kernel(
    const float* __restrict__ hpost, const float* __restrict__ W2,
    const float* __restrict__ att_s2, const float* __restrict__ att_d2,
    float* __restrict__ h2, float* __restrict__ as2, float* __restrict__ ad2, int N)
{
  __shared__ float W2l[128 * 40];
  __shared__ float xrow[4][128];
  const int t = threadIdx.x;
  for (int j = t; j < 128 * 40; j += 256) W2l[j] = W2[j];

  const int w = t >> 6, l = t & 63;
  const int r = blockIdx.x * 4 + w;
  const int lc = l < 40 ? l : 0;
  if (r < N) {
    xrow[w][l] = hpost[(size_t)r * 128 + l];
    xrow[w][l + 64] = hpost[(size_t)r * 128 + 64 + l];
  }
  __syncthreads();
  if (r >= N) return;

  float acc = 0.f;
  #pragma unroll 8
  for (int k = 0; k < 128; ++k) acc += xrow[w][k] * W2l[k * 40 + lc];

  float ps = l < 40 ? acc * att_s2[lc] : 0.f;
  float pd = l < 40 ? acc * att_d2[lc] : 0.f;
  ps = wave_sum64(ps);
  pd = wave_sum64(pd);
  if (l < 40) h2[(size_t)r * 40 + l] = acc;
  if (l == 0) { as2[r] = ps; ad2[r] = pd; }
}

// ---------------------------------------------------------------------------
// Layer-2 aggregation + bias2 + fused log_softmax. One wave per dst node,
// lanes 0..39 own the 40 output channels.
// ---------------------------------------------------------------------------
__global__ __launch_bounds__(256) void agg2_kernel(
    const int* __restrict__ offs, const int* __restrict__ ssrc,
    const float* __restrict__ as2, const float* __restrict__ ad2,
    const float* __restrict__ h2, const float* __restrict__ bias2,
    float* __restrict__ outp, int N)
{
  const int w = threadIdx.x >> 6, l = threadIdx.x & 63;
  const int n = blockIdx.x * 4 + w;
  if (n >= N) return;
  const int lc = l < 40 ? l : 0;
  const float ad = ad2[n];
  const int jb = offs[n], je = offs[n + 1];

  float m = -3.4e38f;
  for (int j = jb; j < je; ++j) {
    float e = as2[ssrc[j]] + ad;
    e = e > 0.f ? e : NEG_SLOPE * e;
    m = fmaxf(m, e);
  }
  float denom = 0.f, acc = 0.f;
  for (int j = jb; j < je; ++j) {
    int s = ssrc[j];
    float e = as2[s] + ad;
    e = e > 0.f ? e : NEG_SLOPE * e;
    float ex = __expf(e - m);
    denom += ex;
    acc += ex * h2[(size_t)s * 40 + lc];
  }
  float o = acc / (denom + 1e-16f) + bias2[lc];
  float vm = l < 40 ? o : -3.4e38f;
  float mx = wave_max64(vm);
  float se = l < 40 ? __expf(o - mx) : 0.f;
  se = wave_sum64(se);
  if (l < 40) outp[(size_t)n * 40 + l] = o - mx - logf(se);
}

// ---------------------------------------------------------------------------
extern "C" void kernel_launch(void* const* d_in, const int* in_sizes, int n_in,
                              void* d_out, int out_size, void* d_ws, size_t ws_size,
                              hipStream_t stream)
{
  const float* x        = (const float*)d_in[0];
  const int*   ei       = (const int*)d_in[1];
  const float* W1       = (const float*)d_in[2];
  const float* att_src1 = (const float*)d_in[3];
  const float* att_dst1 = (const float*)d_in[4];
  const float* bias1    = (const float*)d_in[5];
  const float* bn_gamma = (const float*)d_in[6];
  const float* bn_beta  = (const float*)d_in[7];
  const float* bn_mean  = (const float*)d_in[8];
  const float* bn_var   = (const float*)d_in[9];
  const float* W2       = (const float*)d_in[10];
  const float* att_src2 = (const float*)d_in[11];
  const float* att_dst2 = (const float*)d_in[12];
  const float* bias2    = (const float*)d_in[13];
  const float* W_skip   = (const float*)d_in[14];
  const float* b_skip   = (const float*)d_in[15];

  const int N = in_sizes[0] / 128;
  const int E = in_sizes[1] / 2;
  const int T = E + N;

  char* p = (char*)d_ws;
  auto alloc = [&](size_t bytes) { char* q = p; p += (bytes + 255) & ~255ull; return q; };
  float* h1    = (float*)alloc((size_t)N * 128 * 4);
  float* ident = (float*)alloc((size_t)N * 128 * 4);   // becomes h_post in place
  float* as1   = (float*)alloc((size_t)N * 8 * 4);
  float* ad1   = (float*)alloc((size_t)N * 8 * 4);
  int*   counts= (int*)alloc((size_t)N * 4);
  int*   offs  = (int*)alloc((size_t)(N + 1) * 4);
  int*   cursor= (int*)alloc((size_t)N * 4);
  int*   bsums = (int*)alloc(4096);
  int*   ssrc  = (int*)alloc((size_t)T * 4);
  // dead-buffer reuse for layer 2
  float* h2  = h1;
  float* as2 = as1;
  float* ad2 = ad1;

  const int* ei_src = ei;
  const int* ei_dst = ei + E;

  hipMemsetAsync(counts, 0, (size_t)N * 4, stream);

  dim3 gb((N + 63) / 64, 2);
  gemm128_kernel<0><<<gb, 256, 0, stream>>>(x, W1, nullptr, att_src1, att_dst1,
                                            h1, as1, ad1, N);
  gemm128_kernel<1><<<gb, 256, 0, stream>>>(x, W_skip, b_skip, nullptr, nullptr,
                                            ident, nullptr, nullptr, N);

  count_kernel<<<(T + 255) / 256, 256, 0, stream>>>(ei_dst, counts, E, T);
  int nb = (N + 1023) / 1024;
  scan1_kernel<<<nb, 256, 0, stream>>>(counts, bsums, N);
  scan2_kernel<<<1, 64, 0, stream>>>(bsums, nb);
  scan3_kernel<<<nb, 256, 0, stream>>>(counts, bsums, offs, cursor, N, T);
  scatter_kernel<<<(T + 255) / 256, 256, 0, stream>>>(ei_src, ei_dst, cursor, ssrc, E, T);

  agg1_kernel<<<(N + 3) / 4, 256, 0, stream>>>(offs, ssrc, as1, ad1, h1,
                                               bias1, bn_gamma, bn_beta, bn_mean, bn_var,
                                               ident, N);
  gemm2_kernel<<<(N + 3) / 4, 256, 0, stream>>>(ident, W2, att_src2, att_dst2,
                                                h2, as2, ad2, N);
  agg2_kernel<<<(N + 3) / 4, 256, 0, stream>>>(offs, ssrc, as2, ad2, h2, bias2,
                                               (float*)d_out, N);
}

// Round 2
// 632.222 us; speedup vs baseline: 1.5478x; 1.5478x over previous
//
#include <hip/hip_runtime.h>
#include <math.h>

#define NEG_SLOPE 0.2f
#define BN_EPS 1e-5f

__device__ __forceinline__ float wave_max64(float v) {
  #pragma unroll
  for (int o = 32; o; o >>= 1) v = fmaxf(v, __shfl_xor(v, o, 64));
  return v;
}
__device__ __forceinline__ float wave_sum64(float v) {
  #pragma unroll
  for (int o = 32; o; o >>= 1) v += __shfl_xor(v, o, 64);
  return v;
}

// pack two fp32 into bf16x2 (RNE)
__device__ __forceinline__ unsigned pack2bf(float a, float b) {
  unsigned ua = __float_as_uint(a);
  unsigned ub = __float_as_uint(b);
  ua = ua + 0x7fffu + ((ua >> 16) & 1u);
  ub = ub + 0x7fffu + ((ub >> 16) & 1u);
  return (ua >> 16) | (ub & 0xffff0000u);
}
__device__ __forceinline__ float bf_lo(unsigned u) { return __uint_as_float(u << 16); }
__device__ __forceinline__ float bf_hi(unsigned u) { return __uint_as_float(u & 0xffff0000u); }

// ---------------------------------------------------------------------------
// GEMM (K=128): out[r][cb*64+c] = sum_k X[r][k] * W[k][cb*64+c]
// MODE 0: layer-1 feature GEMM -> bf16 output + per-head alpha_s/alpha_d
// MODE 1: skip projection -> fp32 output + bias
// ---------------------------------------------------------------------------
template<int MODE>
__global__ __launch_bounds__(256) void gemm128_kernel(
    const float* __restrict__ X, const float* __restrict__ W,
    const float* __restrict__ bias,
    const float* __restrict__ att_s, const float* __restrict__ att_d,
    float* __restrict__ out, unsigned* __restrict__ outb,
    float* __restrict__ alpha_s, float* __restrict__ alpha_d,
    int nrows)
{
  __shared__ float Wl[128][64];
  __shared__ float Xt[128][64];   // Xt[k][swz(r)] = X[row0+r][k]
  const int t = threadIdx.x;
  const int cb = blockIdx.y;
  const int row0 = blockIdx.x * 64;

  #pragma unroll
  for (int j = 0; j < 8; ++j) {
    int i4 = j * 256 + t;
    int k = i4 >> 4, c = (i4 & 15) * 4;
    float4 w = *(const float4*)(W + (size_t)k * 128 + cb * 64 + c);
    *(float4*)&Wl[k][c] = w;
  }
  #pragma unroll
  for (int j = 0; j < 8; ++j) {
    int i4 = j * 256 + t;
    int rl = i4 >> 5, kk = (i4 & 31) * 4;
    int r = row0 + rl;
    float4 v = make_float4(0.f, 0.f, 0.f, 0.f);
    if (r < nrows) v = *(const float4*)(X + (size_t)r * 128 + kk);
    int sw = (kk >> 2) & 31;
    int col = (rl & 32) | ((rl & 31) ^ sw);
    Xt[kk + 0][col] = v.x;
    Xt[kk + 1][col] = v.y;
    Xt[kk + 2][col] = v.z;
    Xt[kk + 3][col] = v.w;
  }
  __syncthreads();

  const int cg = t >> 5;
  const int c0 = cg * 8;
  const int rA = t & 31;
  float accA[8] = {0.f, 0.f, 0.f, 0.f, 0.f, 0.f, 0.f, 0.f};
  float accB[8] = {0.f, 0.f, 0.f, 0.f, 0.f, 0.f, 0.f, 0.f};

  #pragma unroll 8
  for (int k = 0; k < 128; ++k) {
    int sw = (k >> 2) & 31;
    float xa = Xt[k][rA ^ sw];
    float xb = Xt[k][32 | (rA ^ sw)];
    float4 w0 = *(float4*)&Wl[k][c0];
    float4 w1 = *(float4*)&Wl[k][c0 + 4];
    accA[0] += xa * w0.x; accA[1] += xa * w0.y; accA[2] += xa * w0.z; accA[3] += xa * w0.w;
    accA[4] += xa * w1.x; accA[5] += xa * w1.y; accA[6] += xa * w1.z; accA[7] += xa * w1.w;
    accB[0] += xb * w0.x; accB[1] += xb * w0.y; accB[2] += xb * w0.z; accB[3] += xb * w0.w;
    accB[4] += xb * w1.x; accB[5] += xb * w1.y; accB[6] += xb * w1.z; accB[7] += xb * w1.w;
  }

  const int gc = cb * 64 + c0;
  const int rGA = row0 + rA, rGB = row0 + rA + 32;

  if (MODE == 1) {
    float b[8];
    #pragma unroll
    for (int j = 0; j < 8; ++j) b[j] = bias[gc + j];
    if (rGA < nrows) {
      float* o = out + (size_t)rGA * 128 + gc;
      *(float4*)o = make_float4(accA[0] + b[0], accA[1] + b[1], accA[2] + b[2], accA[3] + b[3]);
      *(float4*)(o + 4) = make_float4(accA[4] + b[4], accA[5] + b[5], accA[6] + b[6], accA[7] + b[7]);
    }
    if (rGB < nrows) {
      float* o = out + (size_t)rGB * 128 + gc;
      *(float4*)o = make_float4(accB[0] + b[0], accB[1] + b[1], accB[2] + b[2], accB[3] + b[3]);
      *(float4*)(o + 4) = make_float4(accB[4] + b[4], accB[5] + b[5], accB[6] + b[6], accB[7] + b[7]);
    }
  } else {
    // bf16 packed output: row stride 64 uints
    if (rGA < nrows) {
      unsigned* o = outb + (size_t)rGA * 64 + (gc >> 1);
      uint4 v;
      v.x = pack2bf(accA[0], accA[1]); v.y = pack2bf(accA[2], accA[3]);
      v.z = pack2bf(accA[4], accA[5]); v.w = pack2bf(accA[6], accA[7]);
      *(uint4*)o = v;
    }
    if (rGB < nrows) {
      unsigned* o = outb + (size_t)rGB * 64 + (gc >> 1);
      uint4 v;
      v.x = pack2bf(accB[0], accB[1]); v.y = pack2bf(accB[2], accB[3]);
      v.z = pack2bf(accB[4], accB[5]); v.w = pack2bf(accB[6], accB[7]);
      *(uint4*)o = v;
    }
    const int w = t >> 6;
    const int hh = cb * 4 + w;
    const int half = (t >> 5) & 1;
    float psA = 0.f, pdA = 0.f, psB = 0.f, pdB = 0.f;
    #pragma unroll
    for (int j = 0; j < 8; ++j) {
      float as_ = att_s[hh * 16 + half * 8 + j];
      float ad_ = att_d[hh * 16 + half * 8 + j];
      psA += accA[j] * as_; pdA += accA[j] * ad_;
      psB += accB[j] * as_; pdB += accB[j] * ad_;
    }
    psA += __shfl_xor(psA, 32, 64); pdA += __shfl_xor(pdA, 32, 64);
    psB += __shfl_xor(psB, 32, 64); pdB += __shfl_xor(pdB, 32, 64);
    if (half == 0) {
      if (rGA < nrows) { alpha_s[(size_t)rGA * 8 + hh] = psA; alpha_d[(size_t)rGA * 8 + hh] = pdA; }
      if (rGB < nrows) { alpha_s[(size_t)rGB * 8 + hh] = psB; alpha_d[(size_t)rGB * 8 + hh] = pdB; }
    }
  }
}

// ---------------------------------------------------------------------------
// CSR-by-dst construction
// ---------------------------------------------------------------------------
__global__ void count_kernel(const int* __restrict__ dst, int* __restrict__ counts,
                             int E, int T) {
  int i = blockIdx.x * 256 + threadIdx.x;
  if (i < T) {
    int d = (i < E) ? dst[i] : (i - E);
    atomicAdd(&counts[d], 1);
  }
}

__global__ void scan1_kernel(const int* __restrict__ counts, int* __restrict__ bsums, int N) {
  __shared__ int red[256];
  int t = threadIdx.x, b = blockIdx.x;
  int base = b * 1024 + t * 4;
  int s = 0;
  #pragma unroll
  for (int j = 0; j < 4; ++j) { int i = base + j; if (i < N) s += counts[i]; }
  red[t] = s; __syncthreads();
  for (int d = 128; d; d >>= 1) {
    if (t < d) red[t] += red[t + d];
    __syncthreads();
  }
  if (t == 0) bsums[b] = red[0];
}

__global__ void scan2_kernel(int* bsums, int nb) {
  if (threadIdx.x == 0) {
    int run = 0;
    for (int i = 0; i < nb; ++i) { int v = bsums[i]; bsums[i] = run; run += v; }
  }
}

__global__ void scan3_kernel(const int* __restrict__ counts, const int* __restrict__ bsums,
                             int* __restrict__ offs, int* __restrict__ cursor, int N, int total) {
  __shared__ int red[256];
  int t = threadIdx.x, b = blockIdx.x;
  int base = b * 1024 + t * 4;
  int loc[4]; int s = 0;
  #pragma unroll
  for (int j = 0; j < 4; ++j) { int i = base + j; loc[j] = (i < N) ? counts[i] : 0; s += loc[j]; }
  red[t] = s;
  __syncthreads();
  for (int d = 1; d < 256; d <<= 1) {
    int v = (t >= d) ? red[t - d] : 0;
    __syncthreads();
    red[t] += v;
    __syncthreads();
  }
  int excl = red[t] - s + bsums[b];
  #pragma unroll
  for (int j = 0; j < 4; ++j) {
    int i = base + j;
    if (i < N) {
      offs[i] = excl; cursor[i] = excl; excl += loc[j];
      if (i == N - 1) offs[N] = total;
    }
  }
}

__global__ void scatter_kernel(const int* __restrict__ src, const int* __restrict__ dst,
                               int* __restrict__ cursor, int* __restrict__ ssrc, int E, int T) {
  int i = blockIdx.x * 256 + threadIdx.x;
  if (i < T) {
    int s, d;
    if (i < E) { s = src[i]; d = dst[i]; } else { s = d = i - E; }
    int pos = atomicAdd(&cursor[d], 1);
    ssrc[pos] = s;
  }
}

// ---------------------------------------------------------------------------
// Layer-1 aggregation: one wave per dst node, single pass (no max needed:
// e = lrelu(as+ad) is O(1) by construction). lane l -> channels 2l,2l+1,
// head h = l>>3. h1 gathered as packed bf16. Epilogue fuses bias/BN/ELU/skip.
// ---------------------------------------------------------------------------
__global__ __launch_bounds__(256) void agg1_kernel(
    const int* __restrict__ offs, const int* __restrict__ ssrc,
    const float* __restrict__ as1, const float* __restrict__ ad1,
    const unsigned* __restrict__ h1b,
    const float* __restrict__ bias1, const float* __restrict__ gamma,
    const float* __restrict__ beta, const float* __restrict__ mean,
    const float* __restrict__ var,
    float* __restrict__ hpost, int N)
{
  const int w = threadIdx.x >> 6, l = threadIdx.x & 63;
  const int n = blockIdx.x * 4 + w;
  if (n >= N) return;
  const int h = l >> 3;
  const int c0 = l * 2;
  const float ad = ad1[(size_t)n * 8 + h];
  const int jb = offs[n], je = offs[n + 1];

  float denom = 0.f, a0 = 0.f, a1 = 0.f;

#define EDGE1(SS) { \
    float e = as1[(size_t)(SS) * 8 + h] + ad; \
    e = fmaxf(e, NEG_SLOPE * e); \
    float ex = __expf(e); \
    unsigned u = h1b[(size_t)(SS) * 64 + l]; \
    denom += ex; \
    a0 += ex * bf_lo(u); \
    a1 += ex * bf_hi(u); }

  int j = jb;
  for (; j + 4 <= je; j += 4) {
    int s0 = ssrc[j], s1 = ssrc[j + 1], s2 = ssrc[j + 2], s3 = ssrc[j + 3];
    EDGE1(s0) EDGE1(s1) EDGE1(s2) EDGE1(s3)
  }
  for (; j < je; ++j) { int s = ssrc[j]; EDGE1(s) }
#undef EDGE1

  float inv = 1.f / (denom + 1e-16f);
  float2 idv = *(const float2*)(hpost + (size_t)n * 128 + c0);
  float o0 = a0 * inv + bias1[c0];
  float o1 = a1 * inv + bias1[c0 + 1];
  o0 = (o0 - mean[c0]) * (gamma[c0] * rsqrtf(var[c0] + BN_EPS)) + beta[c0];
  o1 = (o1 - mean[c0 + 1]) * (gamma[c0 + 1] * rsqrtf(var[c0 + 1] + BN_EPS)) + beta[c0 + 1];
  o0 = o0 > 0.f ? o0 : expm1f(o0);
  o1 = o1 > 0.f ? o1 : expm1f(o1);
  o0 += idv.x; o1 += idv.y;
  *(float2*)(hpost + (size_t)n * 128 + c0) = make_float2(o0, o1);
}

// ---------------------------------------------------------------------------
// GEMM2: 32 rows per block (8 per wave sequentially), W2 staged once.
// h2 written as packed bf16 [N][20] uints; as2/ad2 via wave reduction.
// ---------------------------------------------------------------------------
__global__ __launch_bounds__(256) void gemm2_kernel(
    const float* __restrict__ hpost, const float* __restrict__ W2,
    const float* __restrict__ att_s2, const float* __restrict__ att_d2,
    unsigned* __restrict__ h2b, float* __restrict__ as2, float* __restrict__ ad2, int N)
{
  __shared__ float W2l[128 * 40];
  __shared__ float xrow[4][128];
  const int t = threadIdx.x;
  const int w = t >> 6, l = t & 63;
  for (int j = t; j < 128 * 40; j += 256) W2l[j] = W2[j];
  __syncthreads();

  const int lc = l < 40 ? l : 0;
  const float as_c = att_s2[lc], ad_c = att_d2[lc];

  for (int rr = 0; rr < 8; ++rr) {
    const int r = blockIdx.x * 32 + rr * 4 + w;
    if (r < N) {
      xrow[w][l] = hpost[(size_t)r * 128 + l];
      xrow[w][l + 64] = hpost[(size_t)r * 128 + 64 + l];
    }
    __syncthreads();
    if (r < N) {
      float acc = 0.f;
      #pragma unroll
      for (int k = 0; k < 128; k += 4) {
        float4 xv = *(float4*)&xrow[w][k];
        acc += xv.x * W2l[(k + 0) * 40 + lc];
        acc += xv.y * W2l[(k + 1) * 40 + lc];
        acc += xv.z * W2l[(k + 2) * 40 + lc];
        acc += xv.w * W2l[(k + 3) * 40 + lc];
      }
      float ps = l < 40 ? acc * as_c : 0.f;
      float pd = l < 40 ? acc * ad_c : 0.f;
      ps = wave_sum64(ps);
      pd = wave_sum64(pd);
      float accP = __shfl_xor(acc, 1, 64);
      if (l < 40 && (l & 1) == 0)
        h2b[(size_t)r * 20 + (l >> 1)] = pack2bf(acc, accP);
      if (l == 0) { as2[r] = ps; ad2[r] = pd; }
    }
    __syncthreads();
  }
}

// ---------------------------------------------------------------------------
// Layer-2 aggregation + bias2 + fused log_softmax. One wave per dst node,
// lanes 0..19 own channel pairs (2l, 2l+1). Single pass, no max.
// ---------------------------------------------------------------------------
__global__ __launch_bounds__(256) void agg2_kernel(
    const int* __restrict__ offs, const int* __restrict__ ssrc,
    const float* __restrict__ as2, const float* __restrict__ ad2,
    const unsigned* __restrict__ h2b, const float* __restrict__ bias2,
    float* __restrict__ outp, int N)
{
  const int w = threadIdx.x >> 6, l = threadIdx.x & 63;
  const int n = blockIdx.x * 4 + w;
  if (n >= N) return;
  const int lc = l < 20 ? l : 0;
  const float ad = ad2[n];
  const int jb = offs[n], je = offs[n + 1];

  float denom = 0.f, a0 = 0.f, a1 = 0.f;

#define EDGE2(SS) { \
    float e = as2[SS] + ad; \
    e = fmaxf(e, NEG_SLOPE * e); \
    float ex = __expf(e); \
    unsigned u = h2b[(size_t)(SS) * 20 + lc]; \
    denom += ex; \
    a0 += ex * bf_lo(u); \
    a1 += ex * bf_hi(u); }

  int j = jb;
  for (; j + 4 <= je; j += 4) {
    int s0 = ssrc[j], s1 = ssrc[j + 1], s2 = ssrc[j + 2], s3 = ssrc[j + 3];
    EDGE2(s0) EDGE2(s1) EDGE2(s2) EDGE2(s3)
  }
  for (; j < je; ++j) { int s = ssrc[j]; EDGE2(s) }
#undef EDGE2

  float inv = 1.f / (denom + 1e-16f);
  float o0 = a0 * inv + bias2[2 * lc];
  float o1 = a1 * inv + bias2[2 * lc + 1];

  float mx = wave_max64(l < 20 ? fmaxf(o0, o1) : -3.4e38f);
  float se = wave_sum64(l < 20 ? __expf(o0 - mx) + __expf(o1 - mx) : 0.f);
  float ls = logf(se);
  if (l < 20)
    *(float2*)&outp[(size_t)n * 40 + 2 * l] = make_float2(o0 - mx - ls, o1 - mx - ls);
}

// ---------------------------------------------------------------------------
extern "C" void kernel_launch(void* const* d_in, const int* in_sizes, int n_in,
                              void* d_out, int out_size, void* d_ws, size_t ws_size,
                              hipStream_t stream)
{
  const float* x        = (const float*)d_in[0];
  const int*   ei       = (const int*)d_in[1];
  const float* W1       = (const float*)d_in[2];
  const float* att_src1 = (const float*)d_in[3];
  const float* att_dst1 = (const float*)d_in[4];
  const float* bias1    = (const float*)d_in[5];
  const float* bn_gamma = (const float*)d_in[6];
  const float* bn_beta  = (const float*)d_in[7];
  const float* bn_mean  = (const float*)d_in[8];
  const float* bn_var   = (const float*)d_in[9];
  const float* W2       = (const float*)d_in[10];
  const float* att_src2 = (const float*)d_in[11];
  const float* att_dst2 = (const float*)d_in[12];
  const float* bias2    = (const float*)d_in[13];
  const float* W_skip   = (const float*)d_in[14];
  const float* b_skip   = (const float*)d_in[15];

  const int N = in_sizes[0] / 128;
  const int E = in_sizes[1] / 2;
  const int T = E + N;

  char* p = (char*)d_ws;
  auto alloc = [&](size_t bytes) { char* q = p; p += (bytes + 255) & ~255ull; return q; };
  unsigned* h1b  = (unsigned*)alloc((size_t)N * 64 * 4);   // bf16x2 packed [N][64]
  float* ident   = (float*)alloc((size_t)N * 128 * 4);     // becomes h_post in place
  float* as1     = (float*)alloc((size_t)N * 8 * 4);
  float* ad1     = (float*)alloc((size_t)N * 8 * 4);
  int*   counts  = (int*)alloc((size_t)N * 4);
  int*   offs    = (int*)alloc((size_t)(N + 1) * 4);
  int*   cursor  = (int*)alloc((size_t)N * 4);
  int*   bsums   = (int*)alloc(4096);
  int*   ssrc    = (int*)alloc((size_t)T * 4);
  // layer-2 reuse of dead layer-1 buffers
  unsigned* h2b  = h1b;               // [N][20] uints, fits in [N][64]
  float* as2 = as1;
  float* ad2 = ad1;

  const int* ei_src = ei;
  const int* ei_dst = ei + E;

  hipMemsetAsync(counts, 0, (size_t)N * 4, stream);

  dim3 gb((N + 63) / 64, 2);
  gemm128_kernel<0><<<gb, 256, 0, stream>>>(x, W1, nullptr, att_src1, att_dst1,
                                            nullptr, h1b, as1, ad1, N);
  gemm128_kernel<1><<<gb, 256, 0, stream>>>(x, W_skip, b_skip, nullptr, nullptr,
                                            ident, nullptr, nullptr, nullptr, N);

  count_kernel<<<(T + 255) / 256, 256, 0, stream>>>(ei_dst, counts, E, T);
  int nb = (N + 1023) / 1024;
  scan1_kernel<<<nb, 256, 0, stream>>>(counts, bsums, N);
  scan2_kernel<<<1, 64, 0, stream>>>(bsums, nb);
  scan3_kernel<<<nb, 256, 0, stream>>>(counts, bsums, offs, cursor, N, T);
  scatter_kernel<<<(T + 255) / 256, 256, 0, stream>>>(ei_src, ei_dst, cursor, ssrc, E, T);

  agg1_kernel<<<(N + 3) / 4, 256, 0, stream>>>(offs, ssrc, as1, ad1, h1b,
                                               bias1, bn_gamma, bn_beta, bn_mean, bn_var,
                                               ident, N);
  gemm2_kernel<<<(N + 31) / 32, 256, 0, stream>>>(ident, W2, att_src2, att_dst2,
                                                  h2b, as2, ad2, N);
  agg2_kernel<<<(N + 3) / 4, 256, 0, stream>>>(offs, ssrc, as2, ad2, h2b, bias2,
                                               (float*)d_out, N);
}

// Round 3
// 462.541 us; speedup vs baseline: 2.1156x; 1.3668x over previous
//
#include <hip/hip_runtime.h>
#include <math.h>

#define NEG_SLOPE 0.2f
#define BN_EPS 1e-5f
#define BSH 9
#define BMASK 511

__device__ __forceinline__ float wave_max64(float v) {
  #pragma unroll
  for (int o = 32; o; o >>= 1) v = fmaxf(v, __shfl_xor(v, o, 64));
  return v;
}
__device__ __forceinline__ float wave_sum64(float v) {
  #pragma unroll
  for (int o = 32; o; o >>= 1) v += __shfl_xor(v, o, 64);
  return v;
}

__device__ __forceinline__ unsigned pack2bf(float a, float b) {
  unsigned ua = __float_as_uint(a);
  unsigned ub = __float_as_uint(b);
  ua = ua + 0x7fffu + ((ua >> 16) & 1u);
  ub = ub + 0x7fffu + ((ub >> 16) & 1u);
  return (ua >> 16) | (ub & 0xffff0000u);
}
__device__ __forceinline__ float bf_lo(unsigned u) { return __uint_as_float(u << 16); }
__device__ __forceinline__ float bf_hi(unsigned u) { return __uint_as_float(u & 0xffff0000u); }

// ---------------------------------------------------------------------------
// Merged layer-1 GEMM: stage X tile once; phase 1: W1 -> h1b (bf16) + alphas;
// phase 2: W_skip -> ident (fp32 + b_skip).
// ---------------------------------------------------------------------------
__global__ __launch_bounds__(256) void gemm1_kernel(
    const float* __restrict__ X, const float* __restrict__ W1,
    const float* __restrict__ Wsk, const float* __restrict__ bsk,
    const float* __restrict__ att_s, const float* __restrict__ att_d,
    unsigned* __restrict__ h1b, float* __restrict__ ident,
    float* __restrict__ alpha_s, float* __restrict__ alpha_d,
    int nrows)
{
  __shared__ float Wl[128][64];
  __shared__ float Xt[128][64];
  const int t = threadIdx.x;
  const int cb = blockIdx.y;
  const int row0 = blockIdx.x * 64;

  // stage X tile transposed + XOR swizzle
  #pragma unroll
  for (int j = 0; j < 8; ++j) {
    int i4 = j * 256 + t;
    int rl = i4 >> 5, kk = (i4 & 31) * 4;
    int r = row0 + rl;
    float4 v = make_float4(0.f, 0.f, 0.f, 0.f);
    if (r < nrows) v = *(const float4*)(X + (size_t)r * 128 + kk);
    int sw = (kk >> 2) & 31;
    int col = (rl & 32) | ((rl & 31) ^ sw);
    Xt[kk + 0][col] = v.x;
    Xt[kk + 1][col] = v.y;
    Xt[kk + 2][col] = v.z;
    Xt[kk + 3][col] = v.w;
  }
  // stage W1 columns
  #pragma unroll
  for (int j = 0; j < 8; ++j) {
    int i4 = j * 256 + t;
    int k = i4 >> 4, c = (i4 & 15) * 4;
    *(float4*)&Wl[k][c] = *(const float4*)(W1 + (size_t)k * 128 + cb * 64 + c);
  }
  __syncthreads();

  const int cg = t >> 5;
  const int c0 = cg * 8;
  const int rA = t & 31;
  const int gc = cb * 64 + c0;
  const int rGA = row0 + rA, rGB = row0 + rA + 32;

  float accA[8], accB[8];
  #pragma unroll
  for (int j = 0; j < 8; ++j) { accA[j] = 0.f; accB[j] = 0.f; }

  #pragma unroll 8
  for (int k = 0; k < 128; ++k) {
    int sw = (k >> 2) & 31;
    float xa = Xt[k][rA ^ sw];
    float xb = Xt[k][32 | (rA ^ sw)];
    float4 w0 = *(float4*)&Wl[k][c0];
    float4 w1 = *(float4*)&Wl[k][c0 + 4];
    accA[0] += xa * w0.x; accA[1] += xa * w0.y; accA[2] += xa * w0.z; accA[3] += xa * w0.w;
    accA[4] += xa * w1.x; accA[5] += xa * w1.y; accA[6] += xa * w1.z; accA[7] += xa * w1.w;
    accB[0] += xb * w0.x; accB[1] += xb * w0.y; accB[2] += xb * w0.z; accB[3] += xb * w0.w;
    accB[4] += xb * w1.x; accB[5] += xb * w1.y; accB[6] += xb * w1.z; accB[7] += xb * w1.w;
  }

  // phase-1 epilogue: bf16 h1 + per-head alphas
  if (rGA < nrows) {
    uint4 v;
    v.x = pack2bf(accA[0], accA[1]); v.y = pack2bf(accA[2], accA[3]);
    v.z = pack2bf(accA[4], accA[5]); v.w = pack2bf(accA[6], accA[7]);
    *(uint4*)(h1b + (size_t)rGA * 64 + (gc >> 1)) = v;
  }
  if (rGB < nrows) {
    uint4 v;
    v.x = pack2bf(accB[0], accB[1]); v.y = pack2bf(accB[2], accB[3]);
    v.z = pack2bf(accB[4], accB[5]); v.w = pack2bf(accB[6], accB[7]);
    *(uint4*)(h1b + (size_t)rGB * 64 + (gc >> 1)) = v;
  }
  {
    const int w = t >> 6;
    const int hh = cb * 4 + w;
    const int half = (t >> 5) & 1;
    float psA = 0.f, pdA = 0.f, psB = 0.f, pdB = 0.f;
    #pragma unroll
    for (int j = 0; j < 8; ++j) {
      float as_ = att_s[hh * 16 + half * 8 + j];
      float ad_ = att_d[hh * 16 + half * 8 + j];
      psA += accA[j] * as_; pdA += accA[j] * ad_;
      psB += accB[j] * as_; pdB += accB[j] * ad_;
    }
    psA += __shfl_xor(psA, 32, 64); pdA += __shfl_xor(pdA, 32, 64);
    psB += __shfl_xor(psB, 32, 64); pdB += __shfl_xor(pdB, 32, 64);
    if (half == 0) {
      if (rGA < nrows) { alpha_s[(size_t)rGA * 8 + hh] = psA; alpha_d[(size_t)rGA * 8 + hh] = pdA; }
      if (rGB < nrows) { alpha_s[(size_t)rGB * 8 + hh] = psB; alpha_d[(size_t)rGB * 8 + hh] = pdB; }
    }
  }

  // phase 2: W_skip against the same X tile
  __syncthreads();
  #pragma unroll
  for (int j = 0; j < 8; ++j) {
    int i4 = j * 256 + t;
    int k = i4 >> 4, c = (i4 & 15) * 4;
    *(float4*)&Wl[k][c] = *(const float4*)(Wsk + (size_t)k * 128 + cb * 64 + c);
  }
  __syncthreads();

  #pragma unroll
  for (int j = 0; j < 8; ++j) { accA[j] = 0.f; accB[j] = 0.f; }

  #pragma unroll 8
  for (int k = 0; k < 128; ++k) {
    int sw = (k >> 2) & 31;
    float xa = Xt[k][rA ^ sw];
    float xb = Xt[k][32 | (rA ^ sw)];
    float4 w0 = *(float4*)&Wl[k][c0];
    float4 w1 = *(float4*)&Wl[k][c0 + 4];
    accA[0] += xa * w0.x; accA[1] += xa * w0.y; accA[2] += xa * w0.z; accA[3] += xa * w0.w;
    accA[4] += xa * w1.x; accA[5] += xa * w1.y; accA[6] += xa * w1.z; accA[7] += xa * w1.w;
    accB[0] += xb * w0.x; accB[1] += xb * w0.y; accB[2] += xb * w0.z; accB[3] += xb * w0.w;
    accB[4] += xb * w1.x; accB[5] += xb * w1.y; accB[6] += xb * w1.z; accB[7] += xb * w1.w;
  }

  float b[8];
  #pragma unroll
  for (int j = 0; j < 8; ++j) b[j] = bsk[gc + j];
  if (rGA < nrows) {
    float* o = ident + (size_t)rGA * 128 + gc;
    *(float4*)o = make_float4(accA[0] + b[0], accA[1] + b[1], accA[2] + b[2], accA[3] + b[3]);
    *(float4*)(o + 4) = make_float4(accA[4] + b[4], accA[5] + b[5], accA[6] + b[6], accA[7] + b[7]);
  }
  if (rGB < nrows) {
    float* o = ident + (size_t)rGB * 128 + gc;
    *(float4*)o = make_float4(accB[0] + b[0], accB[1] + b[1], accB[2] + b[2], accB[3] + b[3]);
    *(float4*)(o + 4) = make_float4(accB[4] + b[4], accB[5] + b[5], accB[6] + b[6], accB[7] + b[7]);
  }
}

// ---------------------------------------------------------------------------
// Bucketed 2-pass sort by dst. Bucket = dst >> 9 (NB <= 256 buckets).
// ---------------------------------------------------------------------------
__global__ __launch_bounds__(256) void hist_kernel(
    const int* __restrict__ src, const int* __restrict__ dst,
    int* __restrict__ bcnt, int E, int T, int chunk, int NB)
{
  __shared__ int hist[256];
  const int t = threadIdx.x;
  hist[t] = 0;
  __syncthreads();
  int s0 = blockIdx.x * chunk;
  int s1 = min(s0 + chunk, T);
  for (int i = s0 + t; i < s1; i += 256) {
    int d = (i < E) ? dst[i] : (i - E);
    atomicAdd(&hist[d >> BSH], 1);
  }
  __syncthreads();
  if (t < NB && hist[t]) atomicAdd(&bcnt[t], hist[t]);
}

__global__ __launch_bounds__(256) void bscan_kernel(
    const int* __restrict__ bcnt, int* __restrict__ bbase, int* __restrict__ bcur, int NB)
{
  __shared__ int ps[256];
  const int t = threadIdx.x;
  int c = (t < NB) ? bcnt[t] : 0;
  ps[t] = c;
  __syncthreads();
  for (int d = 1; d < 256; d <<= 1) {
    int u = (t >= d) ? ps[t - d] : 0;
    __syncthreads();
    ps[t] += u;
    __syncthreads();
  }
  int excl = ps[t] - c;
  if (t <= NB) {
    bbase[t] = excl;
    if (t < NB) bcur[t] = excl;
  }
}

__global__ __launch_bounds__(256) void scatterA_kernel(
    const int* __restrict__ src, const int* __restrict__ dst,
    int* __restrict__ bcur, unsigned* __restrict__ pkbuf,
    int E, int T, int chunk, int NB)
{
  __shared__ int hist[256];
  __shared__ int lbase[256];
  __shared__ int lcur[256];
  const int t = threadIdx.x;
  hist[t] = 0;
  __syncthreads();
  int s0 = blockIdx.x * chunk;
  int s1 = min(s0 + chunk, T);
  for (int i = s0 + t; i < s1; i += 256) {
    int d = (i < E) ? dst[i] : (i - E);
    atomicAdd(&hist[d >> BSH], 1);
  }
  __syncthreads();
  if (t < NB) {
    int h = hist[t];
    lbase[t] = h ? atomicAdd(&bcur[t], h) : 0;
    lcur[t] = 0;
  }
  __syncthreads();
  for (int i = s0 + t; i < s1; i += 256) {
    int d, s;
    if (i < E) { d = dst[i]; s = src[i]; } else { d = s = i - E; }
    int b = d >> BSH;
    int p = lbase[b] + atomicAdd(&lcur[b], 1);
    pkbuf[p] = ((unsigned)(d & BMASK) << 17) | (unsigned)s;
  }
}

// one block per bucket: counting sort of <=512 dst values; emits offs + ssrc
__global__ __launch_bounds__(256) void passB_kernel(
    const unsigned* __restrict__ pkbuf, const int* __restrict__ bbase,
    int* __restrict__ offs, int* __restrict__ ssrc, int N, int T, int NBlast)
{
  __shared__ int cnt[512];
  __shared__ int ps[256];
  __shared__ int cur[512];
  const int t = threadIdx.x;
  const int b = blockIdx.x;
  const int bs = bbase[b], be = bbase[b + 1];

  cnt[t] = 0; cnt[t + 256] = 0;
  __syncthreads();
  for (int i = bs + t; i < be; i += 256)
    atomicAdd(&cnt[pkbuf[i] >> 17], 1);
  __syncthreads();

  int a = cnt[2 * t], b2 = cnt[2 * t + 1];
  ps[t] = a + b2;
  __syncthreads();
  for (int d = 1; d < 256; d <<= 1) {
    int u = (t >= d) ? ps[t - d] : 0;
    __syncthreads();
    ps[t] += u;
    __syncthreads();
  }
  int excl = ps[t] - (a + b2);
  cur[2 * t] = excl;
  cur[2 * t + 1] = excl + a;
  __syncthreads();

  const int node0 = b << BSH;
  #pragma unroll
  for (int jj = 0; jj < 2; ++jj) {
    int d = t + jj * 256;
    int node = node0 + d;
    if (node < N) offs[node] = bs + cur[d];
  }
  if (b == NBlast && t == 0) offs[N] = T;
  __syncthreads();

  for (int i = bs + t; i < be; i += 256) {
    unsigned pk = pkbuf[i];
    int d = pk >> 17;
    int p = atomicAdd(&cur[d], 1);
    ssrc[bs + p] = (int)(pk & 0x1FFFFu);
  }
}

// ---------------------------------------------------------------------------
// Layer-1 aggregation (single pass, no max shift). Writes h_post as bf16.
// ---------------------------------------------------------------------------
__global__ __launch_bounds__(256) void agg1_kernel(
    const int* __restrict__ offs, const int* __restrict__ ssrc,
    const float* __restrict__ as1, const float* __restrict__ ad1,
    const unsigned* __restrict__ h1b,
    const float* __restrict__ bias1, const float* __restrict__ gamma,
    const float* __restrict__ beta, const float* __restrict__ mean,
    const float* __restrict__ var,
    const float* __restrict__ ident, unsigned* __restrict__ hpostb, int N)
{
  const int w = threadIdx.x >> 6, l = threadIdx.x & 63;
  const int n = blockIdx.x * 4 + w;
  if (n >= N) return;
  const int h = l >> 3;
  const int c0 = l * 2;
  const float ad = ad1[(size_t)n * 8 + h];
  const int jb = offs[n], je = offs[n + 1];

  float denom = 0.f, a0 = 0.f, a1 = 0.f;

#define EDGE1(SS) { \
    float e = as1[(size_t)(SS) * 8 + h] + ad; \
    e = fmaxf(e, NEG_SLOPE * e); \
    float ex = __expf(e); \
    unsigned u = h1b[(size_t)(SS) * 64 + l]; \
    denom += ex; \
    a0 += ex * bf_lo(u); \
    a1 += ex * bf_hi(u); }

  int j = jb;
  for (; j + 4 <= je; j += 4) {
    int s0 = ssrc[j], s1 = ssrc[j + 1], s2 = ssrc[j + 2], s3 = ssrc[j + 3];
    EDGE1(s0) EDGE1(s1) EDGE1(s2) EDGE1(s3)
  }
  for (; j < je; ++j) { int s = ssrc[j]; EDGE1(s) }
#undef EDGE1

  float inv = 1.f / (denom + 1e-16f);
  float2 idv = *(const float2*)(ident + (size_t)n * 128 + c0);
  float o0 = a0 * inv + bias1[c0];
  float o1 = a1 * inv + bias1[c0 + 1];
  o0 = (o0 - mean[c0]) * (gamma[c0] * rsqrtf(var[c0] + BN_EPS)) + beta[c0];
  o1 = (o1 - mean[c0 + 1]) * (gamma[c0 + 1] * rsqrtf(var[c0 + 1] + BN_EPS)) + beta[c0 + 1];
  o0 = o0 > 0.f ? o0 : expm1f(o0);
  o1 = o1 > 0.f ? o1 : expm1f(o1);
  o0 += idv.x; o1 += idv.y;
  hpostb[(size_t)n * 64 + l] = pack2bf(o0, o1);
}

// ---------------------------------------------------------------------------
// GEMM2 from bf16 h_post: 32 rows/block, W2 staged once.
// ---------------------------------------------------------------------------
__global__ __launch_bounds__(256) void gemm2_kernel(
    const unsigned* __restrict__ hpostb, const float* __restrict__ W2,
    const float* __restrict__ att_s2, const float* __restrict__ att_d2,
    unsigned* __restrict__ h2b, float* __restrict__ as2, float* __restrict__ ad2, int N)
{
  __shared__ float W2l[128 * 40];
  __shared__ unsigned xrow[4][64];
  const int t = threadIdx.x;
  const int w = t >> 6, l = t & 63;
  for (int j = t; j < 128 * 40; j += 256) W2l[j] = W2[j];
  __syncthreads();

  const int lc = l < 40 ? l : 0;
  const float as_c = att_s2[lc], ad_c = att_d2[lc];

  for (int rr = 0; rr < 8; ++rr) {
    const int r = blockIdx.x * 32 + rr * 4 + w;
    if (r < N) xrow[w][l] = hpostb[(size_t)r * 64 + l];
    __syncthreads();
    if (r < N) {
      float acc = 0.f;
      #pragma unroll
      for (int k2 = 0; k2 < 64; ++k2) {
        unsigned u = xrow[w][k2];
        acc += bf_lo(u) * W2l[(2 * k2) * 40 + lc];
        acc += bf_hi(u) * W2l[(2 * k2 + 1) * 40 + lc];
      }
      float ps = l < 40 ? acc * as_c : 0.f;
      float pd = l < 40 ? acc * ad_c : 0.f;
      ps = wave_sum64(ps);
      pd = wave_sum64(pd);
      float accP = __shfl_xor(acc, 1, 64);
      if (l < 40 && (l & 1) == 0)
        h2b[(size_t)r * 20 + (l >> 1)] = pack2bf(acc, accP);
      if (l == 0) { as2[r] = ps; ad2[r] = pd; }
    }
    __syncthreads();
  }
}

// ---------------------------------------------------------------------------
// Layer-2 aggregation + bias2 + fused log_softmax.
// ---------------------------------------------------------------------------
__global__ __launch_bounds__(256) void agg2_kernel(
    const int* __restrict__ offs, const int* __restrict__ ssrc,
    const float* __restrict__ as2, const float* __restrict__ ad2,
    const unsigned* __restrict__ h2b, const float* __restrict__ bias2,
    float* __restrict__ outp, int N)
{
  const int w = threadIdx.x >> 6, l = threadIdx.x & 63;
  const int n = blockIdx.x * 4 + w;
  if (n >= N) return;
  const int lc = l < 20 ? l : 0;
  const float ad = ad2[n];
  const int jb = offs[n], je = offs[n + 1];

  float denom = 0.f, a0 = 0.f, a1 = 0.f;

#define EDGE2(SS) { \
    float e = as2[SS] + ad; \
    e = fmaxf(e, NEG_SLOPE * e); \
    float ex = __expf(e); \
    unsigned u = h2b[(size_t)(SS) * 20 + lc]; \
    denom += ex; \
    a0 += ex * bf_lo(u); \
    a1 += ex * bf_hi(u); }

  int j = jb;
  for (; j + 4 <= je; j += 4) {
    int s0 = ssrc[j], s1 = ssrc[j + 1], s2 = ssrc[j + 2], s3 = ssrc[j + 3];
    EDGE2(s0) EDGE2(s1) EDGE2(s2) EDGE2(s3)
  }
  for (; j < je; ++j) { int s = ssrc[j]; EDGE2(s) }
#undef EDGE2

  float inv = 1.f / (denom + 1e-16f);
  float o0 = a0 * inv + bias2[2 * lc];
  float o1 = a1 * inv + bias2[2 * lc + 1];

  float mx = wave_max64(l < 20 ? fmaxf(o0, o1) : -3.4e38f);
  float se = wave_sum64(l < 20 ? __expf(o0 - mx) + __expf(o1 - mx) : 0.f);
  float ls = logf(se);
  if (l < 20)
    *(float2*)&outp[(size_t)n * 40 + 2 * l] = make_float2(o0 - mx - ls, o1 - mx - ls);
}

// ---------------------------------------------------------------------------
extern "C" void kernel_launch(void* const* d_in, const int* in_sizes, int n_in,
                              void* d_out, int out_size, void* d_ws, size_t ws_size,
                              hipStream_t stream)
{
  const float* x        = (const float*)d_in[0];
  const int*   ei       = (const int*)d_in[1];
  const float* W1       = (const float*)d_in[2];
  const float* att_src1 = (const float*)d_in[3];
  const float* att_dst1 = (const float*)d_in[4];
  const float* bias1    = (const float*)d_in[5];
  const float* bn_gamma = (const float*)d_in[6];
  const float* bn_beta  = (const float*)d_in[7];
  const float* bn_mean  = (const float*)d_in[8];
  const float* bn_var   = (const float*)d_in[9];
  const float* W2       = (const float*)d_in[10];
  const float* att_src2 = (const float*)d_in[11];
  const float* att_dst2 = (const float*)d_in[12];
  const float* bias2    = (const float*)d_in[13];
  const float* W_skip   = (const float*)d_in[14];
  const float* b_skip   = (const float*)d_in[15];

  const int N = in_sizes[0] / 128;
  const int E = in_sizes[1] / 2;
  const int T = E + N;
  const int NB = (N + BMASK) >> BSH;    // 196 for N=100k (<=256 required)

  char* p = (char*)d_ws;
  auto alloc = [&](size_t bytes) { char* q = p; p += (bytes + 255) & ~255ull; return q; };
  unsigned* h1b    = (unsigned*)alloc((size_t)N * 64 * 4);
  unsigned* hpostb = (unsigned*)alloc((size_t)N * 64 * 4);
  float* ident   = (float*)alloc((size_t)N * 128 * 4);
  float* as1     = (float*)alloc((size_t)N * 8 * 4);
  float* ad1     = (float*)alloc((size_t)N * 8 * 4);
  int*   offs    = (int*)alloc((size_t)(N + 1) * 4);
  unsigned* pkbuf= (unsigned*)alloc((size_t)T * 4);
  int*   ssrc    = (int*)alloc((size_t)T * 4);
  int*   bcnt    = (int*)alloc((size_t)(NB + 1) * 4);
  int*   bbase   = (int*)alloc((size_t)(NB + 1) * 4);
  int*   bcur    = (int*)alloc((size_t)NB * 4);
  // layer-2 reuse of dead layer-1 buffers
  unsigned* h2b = h1b;
  float* as2 = as1;
  float* ad2 = ad1;

  const int* ei_src = ei;
  const int* ei_dst = ei + E;

  hipMemsetAsync(bcnt, 0, (size_t)(NB + 1) * 4, stream);

  dim3 gb((N + 63) / 64, 2);
  gemm1_kernel<<<gb, 256, 0, stream>>>(x, W1, W_skip, b_skip, att_src1, att_dst1,
                                       h1b, ident, as1, ad1, N);

  const int NBLK_A = 512;
  const int chunk = (T + NBLK_A - 1) / NBLK_A;
  hist_kernel<<<NBLK_A, 256, 0, stream>>>(ei_src, ei_dst, bcnt, E, T, chunk, NB);
  bscan_kernel<<<1, 256, 0, stream>>>(bcnt, bbase, bcur, NB);
  scatterA_kernel<<<NBLK_A, 256, 0, stream>>>(ei_src, ei_dst, bcur, pkbuf, E, T, chunk, NB);
  passB_kernel<<<NB, 256, 0, stream>>>(pkbuf, bbase, offs, ssrc, N, T, NB - 1);

  agg1_kernel<<<(N + 3) / 4, 256, 0, stream>>>(offs, ssrc, as1, ad1, h1b,
                                               bias1, bn_gamma, bn_beta, bn_mean, bn_var,
                                               ident, hpostb, N);
  gemm2_kernel<<<(N + 31) / 32, 256, 0, stream>>>(hpostb, W2, att_src2, att_dst2,
                                                  h2b, as2, ad2, N);
  agg2_kernel<<<(N + 3) / 4, 256, 0, stream>>>(offs, ssrc, as2, ad2, h2b, bias2,
                                               (float*)d_out, N);
}

// Round 4
// 389.894 us; speedup vs baseline: 2.5097x; 1.1863x over previous
//
#include <hip/hip_runtime.h>
#include <math.h>

#define NEG_SLOPE 0.2f
#define BN_EPS 1e-5f
#define BSH 9
#define BMASK 511

typedef __attribute__((ext_vector_type(8))) short short8;
typedef __attribute__((ext_vector_type(4))) float f32x4;

__device__ __forceinline__ float wave_max64(float v) {
  #pragma unroll
  for (int o = 32; o; o >>= 1) v = fmaxf(v, __shfl_xor(v, o, 64));
  return v;
}
__device__ __forceinline__ float wave_sum64(float v) {
  #pragma unroll
  for (int o = 32; o; o >>= 1) v += __shfl_xor(v, o, 64);
  return v;
}

__device__ __forceinline__ unsigned pack2bf(float a, float b) {
  unsigned ua = __float_as_uint(a);
  unsigned ub = __float_as_uint(b);
  ua = ua + 0x7fffu + ((ua >> 16) & 1u);
  ub = ub + 0x7fffu + ((ub >> 16) & 1u);
  return (ua >> 16) | (ub & 0xffff0000u);
}
__device__ __forceinline__ unsigned short bf16of(float a) {
  unsigned ua = __float_as_uint(a);
  ua = ua + 0x7fffu + ((ua >> 16) & 1u);
  return (unsigned short)(ua >> 16);
}
__device__ __forceinline__ float bf_lo(unsigned u) { return __uint_as_float(u << 16); }
__device__ __forceinline__ float bf_hi(unsigned u) { return __uint_as_float(u & 0xffff0000u); }

union U8 { short8 s; uint4 u; };

// ---------------------------------------------------------------------------
// prep: Mext[k][0..7] = sum_c W1[k][16h+c]*att_s[h][c]; [8..15] same with att_d
// ---------------------------------------------------------------------------
__global__ void prep_kernel(const float* __restrict__ W1,
                            const float* __restrict__ att_s,
                            const float* __restrict__ att_d,
                            float* __restrict__ Mext)
{
  int k = threadIdx.x;   // 0..127
  #pragma unroll
  for (int h = 0; h < 8; ++h) {
    float s = 0.f, d = 0.f;
    #pragma unroll
    for (int c = 0; c < 16; ++c) {
      float w = W1[k * 128 + h * 16 + c];
      s += w * att_s[h * 16 + c];
      d += w * att_d[h * 16 + c];
    }
    Mext[k * 16 + h] = s;
    Mext[k * 16 + 8 + h] = d;
  }
}

// ---------------------------------------------------------------------------
// MFMA layer-1 GEMM: 128 rows/block, 256 cols (W1 | W_skip) over 4 waves.
// Wave 0,1 -> h1 (bf16) ; wave 0 also computes alphas via Mext B-frag.
// Wave 2,3 -> ident (bf16, +b_skip). A tile bf16 in LDS, XOR-swizzled.
// ---------------------------------------------------------------------------
__global__ __launch_bounds__(256) void gemm1_kernel(
    const float* __restrict__ X, const float* __restrict__ W1,
    const float* __restrict__ Wsk, const float* __restrict__ bsk,
    const float* __restrict__ Mext,
    unsigned short* __restrict__ h1u, unsigned short* __restrict__ identu,
    float* __restrict__ alpha_s, float* __restrict__ alpha_d, int N)
{
  __shared__ uint4 Asm4[2048];           // 32 KB: [128 rows][128 bf16]
  const int t = threadIdx.x;
  const int l = t & 63, wave = t >> 6;
  const int lx = l & 15, ly = l >> 4;
  const int row0 = blockIdx.x * 128;
  const int wn0 = wave * 64;

  // ---- B fragments from global (L2-hot W), bf16-packed, held in VGPRs ----
  short8 b[4][4];
  short8 b4[4] = {};
  #pragma unroll
  for (int nf = 0; nf < 4; ++nf) {
    int c = wn0 + nf * 16 + lx;
    const float* bp = (c < 128) ? (W1 + c) : (Wsk + c - 128);
    #pragma unroll
    for (int kf = 0; kf < 4; ++kf) {
      int k0 = kf * 32 + ly * 8;
      U8 f;
      f.u.x = pack2bf(bp[(k0 + 0) * 128], bp[(k0 + 1) * 128]);
      f.u.y = pack2bf(bp[(k0 + 2) * 128], bp[(k0 + 3) * 128]);
      f.u.z = pack2bf(bp[(k0 + 4) * 128], bp[(k0 + 5) * 128]);
      f.u.w = pack2bf(bp[(k0 + 6) * 128], bp[(k0 + 7) * 128]);
      b[nf][kf] = f.s;
    }
  }
  if (wave == 0) {
    const float* bp = Mext + lx;
    #pragma unroll
    for (int kf = 0; kf < 4; ++kf) {
      int k0 = kf * 32 + ly * 8;
      U8 f;
      f.u.x = pack2bf(bp[(k0 + 0) * 16], bp[(k0 + 1) * 16]);
      f.u.y = pack2bf(bp[(k0 + 2) * 16], bp[(k0 + 3) * 16]);
      f.u.z = pack2bf(bp[(k0 + 4) * 16], bp[(k0 + 5) * 16]);
      f.u.w = pack2bf(bp[(k0 + 6) * 16], bp[(k0 + 7) * 16]);
      b4[kf] = f.s;
    }
  }

  // ---- stage A tile: fp32 -> bf16, swizzled LDS ----
  {
    int rl = t >> 1;                 // local row 0..127
    int half = t & 1;                // k half
    int r = row0 + rl;
    const float* xp = X + (size_t)r * 128 + half * 64;
    #pragma unroll
    for (int i = 0; i < 8; ++i) {
      float4 f0 = make_float4(0.f, 0.f, 0.f, 0.f), f1 = f0;
      if (r < N) {
        f0 = *(const float4*)(xp + i * 8);
        f1 = *(const float4*)(xp + i * 8 + 4);
      }
      uint4 u;
      u.x = pack2bf(f0.x, f0.y); u.y = pack2bf(f0.z, f0.w);
      u.z = pack2bf(f1.x, f1.y); u.w = pack2bf(f1.z, f1.w);
      int woff = (rl * 256 + half * 128 + i * 16) ^ ((rl & 7) << 4);
      *(uint4*)((char*)Asm4 + woff) = u;
    }
  }
  __syncthreads();

  float bval[4];
  if (wave >= 2) {
    #pragma unroll
    for (int nf = 0; nf < 4; ++nf) bval[nf] = bsk[(wave - 2) * 64 + nf * 16 + lx];
  }

  // ---- main loop over 8 m-fragments ----
  for (int mf = 0; mf < 8; ++mf) {
    short8 a[4];
    int rowl = mf * 16 + lx;
    #pragma unroll
    for (int kf = 0; kf < 4; ++kf)
      a[kf] = *(short8*)((char*)Asm4 + ((rowl * 256 + kf * 64 + ly * 16) ^ ((lx & 7) << 4)));

    int rbase = row0 + mf * 16 + ly * 4;

    #pragma unroll
    for (int nf = 0; nf < 4; ++nf) {
      f32x4 acc = {0.f, 0.f, 0.f, 0.f};
      #pragma unroll
      for (int kf = 0; kf < 4; ++kf)
        acc = __builtin_amdgcn_mfma_f32_16x16x32_bf16(a[kf], b[nf][kf], acc, 0, 0, 0);
      if (wave < 2) {
        int c = wn0 + nf * 16 + lx;
        #pragma unroll
        for (int reg = 0; reg < 4; ++reg) {
          int r = rbase + reg;
          if (r < N) h1u[(size_t)r * 128 + c] = bf16of(acc[reg]);
        }
      } else {
        int c = (wave - 2) * 64 + nf * 16 + lx;
        #pragma unroll
        for (int reg = 0; reg < 4; ++reg) {
          int r = rbase + reg;
          if (r < N) identu[(size_t)r * 128 + c] = bf16of(acc[reg] + bval[nf]);
        }
      }
    }

    if (wave == 0) {
      f32x4 acc = {0.f, 0.f, 0.f, 0.f};
      #pragma unroll
      for (int kf = 0; kf < 4; ++kf)
        acc = __builtin_amdgcn_mfma_f32_16x16x32_bf16(a[kf], b4[kf], acc, 0, 0, 0);
      #pragma unroll
      for (int reg = 0; reg < 4; ++reg) {
        int r = rbase + reg;
        if (r < N) {
          if (lx < 8) alpha_s[(size_t)r * 8 + lx] = acc[reg];
          else        alpha_d[(size_t)r * 8 + (lx - 8)] = acc[reg];
        }
      }
    }
  }
}

// ---------------------------------------------------------------------------
// Bucketed 2-pass sort by dst. Bucket = dst >> 9 (NB <= 256 buckets).
// ---------------------------------------------------------------------------
__global__ __launch_bounds__(256) void hist_kernel(
    const int* __restrict__ src, const int* __restrict__ dst,
    int* __restrict__ bcnt, int E, int T, int chunk, int NB)
{
  __shared__ int hist[256];
  const int t = threadIdx.x;
  hist[t] = 0;
  __syncthreads();
  int s0 = blockIdx.x * chunk;
  int s1 = min(s0 + chunk, T);
  for (int i = s0 + t; i < s1; i += 256) {
    int d = (i < E) ? dst[i] : (i - E);
    atomicAdd(&hist[d >> BSH], 1);
  }
  __syncthreads();
  if (t < NB && hist[t]) atomicAdd(&bcnt[t], hist[t]);
}

__global__ __launch_bounds__(256) void bscan_kernel(
    const int* __restrict__ bcnt, int* __restrict__ bbase, int* __restrict__ bcur, int NB)
{
  __shared__ int ps[256];
  const int t = threadIdx.x;
  int c = (t < NB) ? bcnt[t] : 0;
  ps[t] = c;
  __syncthreads();
  for (int d = 1; d < 256; d <<= 1) {
    int u = (t >= d) ? ps[t - d] : 0;
    __syncthreads();
    ps[t] += u;
    __syncthreads();
  }
  int excl = ps[t] - c;
  if (t <= NB) {
    bbase[t] = excl;
    if (t < NB) bcur[t] = excl;
  }
}

__global__ __launch_bounds__(256) void scatterA_kernel(
    const int* __restrict__ src, const int* __restrict__ dst,
    int* __restrict__ bcur, unsigned* __restrict__ pkbuf,
    int E, int T, int chunk, int NB)
{
  __shared__ int hist[256];
  __shared__ int lbase[256];
  __shared__ int lcur[256];
  const int t = threadIdx.x;
  hist[t] = 0;
  __syncthreads();
  int s0 = blockIdx.x * chunk;
  int s1 = min(s0 + chunk, T);
  for (int i = s0 + t; i < s1; i += 256) {
    int d = (i < E) ? dst[i] : (i - E);
    atomicAdd(&hist[d >> BSH], 1);
  }
  __syncthreads();
  if (t < NB) {
    int h = hist[t];
    lbase[t] = h ? atomicAdd(&bcur[t], h) : 0;
    lcur[t] = 0;
  }
  __syncthreads();
  for (int i = s0 + t; i < s1; i += 256) {
    int d, s;
    if (i < E) { d = dst[i]; s = src[i]; } else { d = s = i - E; }
    int b = d >> BSH;
    int p = lbase[b] + atomicAdd(&lcur[b], 1);
    pkbuf[p] = ((unsigned)(d & BMASK) << 17) | (unsigned)s;
  }
}

__global__ __launch_bounds__(256) void passB_kernel(
    const unsigned* __restrict__ pkbuf, const int* __restrict__ bbase,
    int* __restrict__ offs, int* __restrict__ ssrc, int N, int T, int NBlast)
{
  __shared__ int cnt[512];
  __shared__ int ps[256];
  __shared__ int cur[512];
  const int t = threadIdx.x;
  const int b = blockIdx.x;
  const int bs = bbase[b], be = bbase[b + 1];

  cnt[t] = 0; cnt[t + 256] = 0;
  __syncthreads();
  for (int i = bs + t; i < be; i += 256)
    atomicAdd(&cnt[pkbuf[i] >> 17], 1);
  __syncthreads();

  int a = cnt[2 * t], b2 = cnt[2 * t + 1];
  ps[t] = a + b2;
  __syncthreads();
  for (int d = 1; d < 256; d <<= 1) {
    int u = (t >= d) ? ps[t - d] : 0;
    __syncthreads();
    ps[t] += u;
    __syncthreads();
  }
  int excl = ps[t] - (a + b2);
  cur[2 * t] = excl;
  cur[2 * t + 1] = excl + a;
  __syncthreads();

  const int node0 = b << BSH;
  #pragma unroll
  for (int jj = 0; jj < 2; ++jj) {
    int d = t + jj * 256;
    int node = node0 + d;
    if (node < N) offs[node] = bs + cur[d];
  }
  if (b == NBlast && t == 0) offs[N] = T;
  __syncthreads();

  for (int i = bs + t; i < be; i += 256) {
    unsigned pk = pkbuf[i];
    int d = pk >> 17;
    int p = atomicAdd(&cur[d], 1);
    ssrc[bs + p] = (int)(pk & 0x1FFFFu);
  }
}

// ---------------------------------------------------------------------------
// Layer-1 aggregation (single pass, no max shift). bf16 gathers; bf16 h_post.
// ---------------------------------------------------------------------------
__global__ __launch_bounds__(256) void agg1_kernel(
    const int* __restrict__ offs, const int* __restrict__ ssrc,
    const float* __restrict__ as1, const float* __restrict__ ad1,
    const unsigned* __restrict__ h1b,
    const float* __restrict__ bias1, const float* __restrict__ gamma,
    const float* __restrict__ beta, const float* __restrict__ mean,
    const float* __restrict__ var,
    const unsigned* __restrict__ identb, unsigned* __restrict__ hpostb, int N)
{
  const int w = threadIdx.x >> 6, l = threadIdx.x & 63;
  const int n = blockIdx.x * 4 + w;
  if (n >= N) return;
  const int h = l >> 3;
  const int c0 = l * 2;
  const float ad = ad1[(size_t)n * 8 + h];
  const int jb = offs[n], je = offs[n + 1];

  float denom = 0.f, a0 = 0.f, a1 = 0.f;

#define EDGE1(SS) { \
    float e = as1[(size_t)(SS) * 8 + h] + ad; \
    e = fmaxf(e, NEG_SLOPE * e); \
    float ex = __expf(e); \
    unsigned u = h1b[(size_t)(SS) * 64 + l]; \
    denom += ex; \
    a0 += ex * bf_lo(u); \
    a1 += ex * bf_hi(u); }

  int j = jb;
  for (; j + 4 <= je; j += 4) {
    int s0 = ssrc[j], s1 = ssrc[j + 1], s2 = ssrc[j + 2], s3 = ssrc[j + 3];
    EDGE1(s0) EDGE1(s1) EDGE1(s2) EDGE1(s3)
  }
  for (; j < je; ++j) { int s = ssrc[j]; EDGE1(s) }
#undef EDGE1

  float inv = 1.f / (denom + 1e-16f);
  unsigned uid = identb[(size_t)n * 64 + l];
  float o0 = a0 * inv + bias1[c0];
  float o1 = a1 * inv + bias1[c0 + 1];
  o0 = (o0 - mean[c0]) * (gamma[c0] * rsqrtf(var[c0] + BN_EPS)) + beta[c0];
  o1 = (o1 - mean[c0 + 1]) * (gamma[c0 + 1] * rsqrtf(var[c0 + 1] + BN_EPS)) + beta[c0 + 1];
  o0 = o0 > 0.f ? o0 : expm1f(o0);
  o1 = o1 > 0.f ? o1 : expm1f(o1);
  o0 += bf_lo(uid); o1 += bf_hi(uid);
  hpostb[(size_t)n * 64 + l] = pack2bf(o0, o1);
}

// ---------------------------------------------------------------------------
// GEMM2 from bf16 h_post: 32 rows/block, W2 staged once.
// ---------------------------------------------------------------------------
__global__ __launch_bounds__(256) void gemm2_kernel(
    const unsigned* __restrict__ hpostb, const float* __restrict__ W2,
    const float* __restrict__ att_s2, const float* __restrict__ att_d2,
    unsigned* __restrict__ h2b, float* __restrict__ as2, float* __restrict__ ad2, int N)
{
  __shared__ float W2l[128 * 40];
  __shared__ unsigned xrow[4][64];
  const int t = threadIdx.x;
  const int w = t >> 6, l = t & 63;
  for (int j = t; j < 128 * 40; j += 256) W2l[j] = W2[j];
  __syncthreads();

  const int lc = l < 40 ? l : 0;
  const float as_c = att_s2[lc], ad_c = att_d2[lc];

  for (int rr = 0; rr < 8; ++rr) {
    const int r = blockIdx.x * 32 + rr * 4 + w;
    if (r < N) xrow[w][l] = hpostb[(size_t)r * 64 + l];
    __syncthreads();
    if (r < N) {
      float acc = 0.f;
      #pragma unroll
      for (int k2 = 0; k2 < 64; ++k2) {
        unsigned u = xrow[w][k2];
        acc += bf_lo(u) * W2l[(2 * k2) * 40 + lc];
        acc += bf_hi(u) * W2l[(2 * k2 + 1) * 40 + lc];
      }
      float ps = l < 40 ? acc * as_c : 0.f;
      float pd = l < 40 ? acc * ad_c : 0.f;
      ps = wave_sum64(ps);
      pd = wave_sum64(pd);
      float accP = __shfl_xor(acc, 1, 64);
      if (l < 40 && (l & 1) == 0)
        h2b[(size_t)r * 20 + (l >> 1)] = pack2bf(acc, accP);
      if (l == 0) { as2[r] = ps; ad2[r] = pd; }
    }
    __syncthreads();
  }
}

// ---------------------------------------------------------------------------
// Layer-2 aggregation + bias2 + fused log_softmax.
// ---------------------------------------------------------------------------
__global__ __launch_bounds__(256) void agg2_kernel(
    const int* __restrict__ offs, const int* __restrict__ ssrc,
    const float* __restrict__ as2, const float* __restrict__ ad2,
    const unsigned* __restrict__ h2b, const float* __restrict__ bias2,
    float* __restrict__ outp, int N)
{
  const int w = threadIdx.x >> 6, l = threadIdx.x & 63;
  const int n = blockIdx.x * 4 + w;
  if (n >= N) return;
  const int lc = l < 20 ? l : 0;
  const float ad = ad2[n];
  const int jb = offs[n], je = offs[n + 1];

  float denom = 0.f, a0 = 0.f, a1 = 0.f;

#define EDGE2(SS) { \
    float e = as2[SS] + ad; \
    e = fmaxf(e, NEG_SLOPE * e); \
    float ex = __expf(e); \
    unsigned u = h2b[(size_t)(SS) * 20 + lc]; \
    denom += ex; \
    a0 += ex * bf_lo(u); \
    a1 += ex * bf_hi(u); }

  int j = jb;
  for (; j + 4 <= je; j += 4) {
    int s0 = ssrc[j], s1 = ssrc[j + 1], s2 = ssrc[j + 2], s3 = ssrc[j + 3];
    EDGE2(s0) EDGE2(s1) EDGE2(s2) EDGE2(s3)
  }
  for (; j < je; ++j) { int s = ssrc[j]; EDGE2(s) }
#undef EDGE2

  float inv = 1.f / (denom + 1e-16f);
  float o0 = a0 * inv + bias2[2 * lc];
  float o1 = a1 * inv + bias2[2 * lc + 1];

  float mx = wave_max64(l < 20 ? fmaxf(o0, o1) : -3.4e38f);
  float se = wave_sum64(l < 20 ? __expf(o0 - mx) + __expf(o1 - mx) : 0.f);
  float ls = logf(se);
  if (l < 20)
    *(float2*)&outp[(size_t)n * 40 + 2 * l] = make_float2(o0 - mx - ls, o1 - mx - ls);
}

// ---------------------------------------------------------------------------
extern "C" void kernel_launch(void* const* d_in, const int* in_sizes, int n_in,
                              void* d_out, int out_size, void* d_ws, size_t ws_size,
                              hipStream_t stream)
{
  const float* x        = (const float*)d_in[0];
  const int*   ei       = (const int*)d_in[1];
  const float* W1       = (const float*)d_in[2];
  const float* att_src1 = (const float*)d_in[3];
  const float* att_dst1 = (const float*)d_in[4];
  const float* bias1    = (const float*)d_in[5];
  const float* bn_gamma = (const float*)d_in[6];
  const float* bn_beta  = (const float*)d_in[7];
  const float* bn_mean  = (const float*)d_in[8];
  const float* bn_var   = (const float*)d_in[9];
  const float* W2       = (const float*)d_in[10];
  const float* att_src2 = (const float*)d_in[11];
  const float* att_dst2 = (const float*)d_in[12];
  const float* bias2    = (const float*)d_in[13];
  const float* W_skip   = (const float*)d_in[14];
  const float* b_skip   = (const float*)d_in[15];

  const int N = in_sizes[0] / 128;
  const int E = in_sizes[1] / 2;
  const int T = E + N;
  const int NB = (N + BMASK) >> BSH;

  char* p = (char*)d_ws;
  auto alloc = [&](size_t bytes) { char* q = p; p += (bytes + 255) & ~255ull; return q; };
  unsigned* h1b    = (unsigned*)alloc((size_t)N * 64 * 4);   // bf16 [N][128]
  unsigned* hpostb = (unsigned*)alloc((size_t)N * 64 * 4);
  unsigned* identb = (unsigned*)alloc((size_t)N * 64 * 4);   // bf16 [N][128]
  float* as1     = (float*)alloc((size_t)N * 8 * 4);
  float* ad1     = (float*)alloc((size_t)N * 8 * 4);
  float* Mext    = (float*)alloc(128 * 16 * 4);
  int*   offs    = (int*)alloc((size_t)(N + 1) * 4);
  unsigned* pkbuf= (unsigned*)alloc((size_t)T * 4);
  int*   ssrc    = (int*)alloc((size_t)T * 4);
  int*   bcnt    = (int*)alloc((size_t)(NB + 1) * 4);
  int*   bbase   = (int*)alloc((size_t)(NB + 1) * 4);
  int*   bcur    = (int*)alloc((size_t)NB * 4);
  unsigned* h2b = h1b;
  float* as2 = as1;
  float* ad2 = ad1;

  const int* ei_src = ei;
  const int* ei_dst = ei + E;

  hipMemsetAsync(bcnt, 0, (size_t)(NB + 1) * 4, stream);

  prep_kernel<<<1, 128, 0, stream>>>(W1, att_src1, att_dst1, Mext);
  gemm1_kernel<<<(N + 127) / 128, 256, 0, stream>>>(
      x, W1, W_skip, b_skip, Mext,
      (unsigned short*)h1b, (unsigned short*)identb, as1, ad1, N);

  const int NBLK_A = 512;
  const int chunk = (T + NBLK_A - 1) / NBLK_A;
  hist_kernel<<<NBLK_A, 256, 0, stream>>>(ei_src, ei_dst, bcnt, E, T, chunk, NB);
  bscan_kernel<<<1, 256, 0, stream>>>(bcnt, bbase, bcur, NB);
  scatterA_kernel<<<NBLK_A, 256, 0, stream>>>(ei_src, ei_dst, bcur, pkbuf, E, T, chunk, NB);
  passB_kernel<<<NB, 256, 0, stream>>>(pkbuf, bbase, offs, ssrc, N, T, NB - 1);

  agg1_kernel<<<(N + 3) / 4, 256, 0, stream>>>(offs, ssrc, as1, ad1, h1b,
                                               bias1, bn_gamma, bn_beta, bn_mean, bn_var,
                                               identb, hpostb, N);
  gemm2_kernel<<<(N + 31) / 32, 256, 0, stream>>>(hpostb, W2, att_src2, att_dst2,
                                                  h2b, as2, ad2, N);
  agg2_kernel<<<(N + 3) / 4, 256, 0, stream>>>(offs, ssrc, as2, ad2, h2b, bias2,
                                               (float*)d_out, N);
}

// Round 5
// 309.791 us; speedup vs baseline: 3.1587x; 1.2586x over previous
//
#include <hip/hip_runtime.h>
#include <math.h>

#define NEG_SLOPE 0.2f
#define BN_EPS 1e-5f
#define BSH 9
#define BMASK 511

typedef __attribute__((ext_vector_type(8))) short short8;
typedef __attribute__((ext_vector_type(4))) float f32x4;

__device__ __forceinline__ float wave_max64(float v) {
  #pragma unroll
  for (int o = 32; o; o >>= 1) v = fmaxf(v, __shfl_xor(v, o, 64));
  return v;
}
__device__ __forceinline__ float wave_sum64(float v) {
  #pragma unroll
  for (int o = 32; o; o >>= 1) v += __shfl_xor(v, o, 64);
  return v;
}

__device__ __forceinline__ unsigned pack2bf(float a, float b) {
  unsigned ua = __float_as_uint(a);
  unsigned ub = __float_as_uint(b);
  ua = ua + 0x7fffu + ((ua >> 16) & 1u);
  ub = ub + 0x7fffu + ((ub >> 16) & 1u);
  return (ua >> 16) | (ub & 0xffff0000u);
}
__device__ __forceinline__ unsigned short bf16of(float a) {
  unsigned ua = __float_as_uint(a);
  ua = ua + 0x7fffu + ((ua >> 16) & 1u);
  return (unsigned short)(ua >> 16);
}
__device__ __forceinline__ float bf_lo(unsigned u) { return __uint_as_float(u << 16); }
__device__ __forceinline__ float bf_hi(unsigned u) { return __uint_as_float(u & 0xffff0000u); }

union U8 { short8 s; uint4 u; };

// ---------------------------------------------------------------------------
// prep: Mext[k][0..7]=W1[k]·att_s per head, [8..15] att_d (layer1)
//       M2ext[k][0]=W2[k]·att_s2, [1]=W2[k]·att_d2 (layer2)
// ---------------------------------------------------------------------------
__global__ void prep_kernel(const float* __restrict__ W1,
                            const float* __restrict__ att_s,
                            const float* __restrict__ att_d,
                            float* __restrict__ Mext,
                            const float* __restrict__ W2,
                            const float* __restrict__ att_s2,
                            const float* __restrict__ att_d2,
                            float* __restrict__ M2ext)
{
  int k = threadIdx.x;   // 0..127
  #pragma unroll
  for (int h = 0; h < 8; ++h) {
    float s = 0.f, d = 0.f;
    #pragma unroll
    for (int c = 0; c < 16; ++c) {
      float w = W1[k * 128 + h * 16 + c];
      s += w * att_s[h * 16 + c];
      d += w * att_d[h * 16 + c];
    }
    Mext[k * 16 + h] = s;
    Mext[k * 16 + 8 + h] = d;
  }
  float s2 = 0.f, d2 = 0.f;
  #pragma unroll
  for (int c = 0; c < 40; ++c) {
    float w = W2[k * 40 + c];
    s2 += w * att_s2[c];
    d2 += w * att_d2[c];
  }
  M2ext[k * 2] = s2;
  M2ext[k * 2 + 1] = d2;
}

// ---------------------------------------------------------------------------
// MFMA layer-1 GEMM: 128 rows/block, 256 cols (W1 | W_skip) over 4 waves.
// ---------------------------------------------------------------------------
__global__ __launch_bounds__(256) void gemm1_kernel(
    const float* __restrict__ X, const float* __restrict__ W1,
    const float* __restrict__ Wsk, const float* __restrict__ bsk,
    const float* __restrict__ Mext,
    unsigned short* __restrict__ h1u, unsigned short* __restrict__ identu,
    float* __restrict__ alpha_s, float* __restrict__ alpha_d, int N)
{
  __shared__ uint4 Asm4[2048];           // 32 KB: [128 rows][128 bf16]
  const int t = threadIdx.x;
  const int l = t & 63, wave = t >> 6;
  const int lx = l & 15, ly = l >> 4;
  const int row0 = blockIdx.x * 128;
  const int wn0 = wave * 64;

  short8 b[4][4];
  short8 b4[4] = {};
  #pragma unroll
  for (int nf = 0; nf < 4; ++nf) {
    int c = wn0 + nf * 16 + lx;
    const float* bp = (c < 128) ? (W1 + c) : (Wsk + c - 128);
    #pragma unroll
    for (int kf = 0; kf < 4; ++kf) {
      int k0 = kf * 32 + ly * 8;
      U8 f;
      f.u.x = pack2bf(bp[(k0 + 0) * 128], bp[(k0 + 1) * 128]);
      f.u.y = pack2bf(bp[(k0 + 2) * 128], bp[(k0 + 3) * 128]);
      f.u.z = pack2bf(bp[(k0 + 4) * 128], bp[(k0 + 5) * 128]);
      f.u.w = pack2bf(bp[(k0 + 6) * 128], bp[(k0 + 7) * 128]);
      b[nf][kf] = f.s;
    }
  }
  if (wave == 0) {
    const float* bp = Mext + lx;
    #pragma unroll
    for (int kf = 0; kf < 4; ++kf) {
      int k0 = kf * 32 + ly * 8;
      U8 f;
      f.u.x = pack2bf(bp[(k0 + 0) * 16], bp[(k0 + 1) * 16]);
      f.u.y = pack2bf(bp[(k0 + 2) * 16], bp[(k0 + 3) * 16]);
      f.u.z = pack2bf(bp[(k0 + 4) * 16], bp[(k0 + 5) * 16]);
      f.u.w = pack2bf(bp[(k0 + 6) * 16], bp[(k0 + 7) * 16]);
      b4[kf] = f.s;
    }
  }

  {
    int rl = t >> 1;
    int half = t & 1;
    int r = row0 + rl;
    const float* xp = X + (size_t)r * 128 + half * 64;
    #pragma unroll
    for (int i = 0; i < 8; ++i) {
      float4 f0 = make_float4(0.f, 0.f, 0.f, 0.f), f1 = f0;
      if (r < N) {
        f0 = *(const float4*)(xp + i * 8);
        f1 = *(const float4*)(xp + i * 8 + 4);
      }
      uint4 u;
      u.x = pack2bf(f0.x, f0.y); u.y = pack2bf(f0.z, f0.w);
      u.z = pack2bf(f1.x, f1.y); u.w = pack2bf(f1.z, f1.w);
      int woff = (rl * 256 + half * 128 + i * 16) ^ ((rl & 7) << 4);
      *(uint4*)((char*)Asm4 + woff) = u;
    }
  }
  __syncthreads();

  float bval[4];
  if (wave >= 2) {
    #pragma unroll
    for (int nf = 0; nf < 4; ++nf) bval[nf] = bsk[(wave - 2) * 64 + nf * 16 + lx];
  }

  for (int mf = 0; mf < 8; ++mf) {
    short8 a[4];
    int rowl = mf * 16 + lx;
    #pragma unroll
    for (int kf = 0; kf < 4; ++kf)
      a[kf] = *(short8*)((char*)Asm4 + ((rowl * 256 + kf * 64 + ly * 16) ^ ((lx & 7) << 4)));

    int rbase = row0 + mf * 16 + ly * 4;

    #pragma unroll
    for (int nf = 0; nf < 4; ++nf) {
      f32x4 acc = {0.f, 0.f, 0.f, 0.f};
      #pragma unroll
      for (int kf = 0; kf < 4; ++kf)
        acc = __builtin_amdgcn_mfma_f32_16x16x32_bf16(a[kf], b[nf][kf], acc, 0, 0, 0);
      if (wave < 2) {
        int c = wn0 + nf * 16 + lx;
        #pragma unroll
        for (int reg = 0; reg < 4; ++reg) {
          int r = rbase + reg;
          if (r < N) h1u[(size_t)r * 128 + c] = bf16of(acc[reg]);
        }
      } else {
        int c = (wave - 2) * 64 + nf * 16 + lx;
        #pragma unroll
        for (int reg = 0; reg < 4; ++reg) {
          int r = rbase + reg;
          if (r < N) identu[(size_t)r * 128 + c] = bf16of(acc[reg] + bval[nf]);
        }
      }
    }

    if (wave == 0) {
      f32x4 acc = {0.f, 0.f, 0.f, 0.f};
      #pragma unroll
      for (int kf = 0; kf < 4; ++kf)
        acc = __builtin_amdgcn_mfma_f32_16x16x32_bf16(a[kf], b4[kf], acc, 0, 0, 0);
      #pragma unroll
      for (int reg = 0; reg < 4; ++reg) {
        int r = rbase + reg;
        if (r < N) {
          if (lx < 8) alpha_s[(size_t)r * 8 + lx] = acc[reg];
          else        alpha_d[(size_t)r * 8 + (lx - 8)] = acc[reg];
        }
      }
    }
  }
}

// ---------------------------------------------------------------------------
// Bucketed 2-pass sort by dst.
// ---------------------------------------------------------------------------
__global__ __launch_bounds__(256) void hist_kernel(
    const int* __restrict__ src, const int* __restrict__ dst,
    int* __restrict__ bcnt, int E, int T, int chunk, int NB)
{
  __shared__ int hist[256];
  const int t = threadIdx.x;
  hist[t] = 0;
  __syncthreads();
  int s0 = blockIdx.x * chunk;
  int s1 = min(s0 + chunk, T);
  for (int i = s0 + t; i < s1; i += 256) {
    int d = (i < E) ? dst[i] : (i - E);
    atomicAdd(&hist[d >> BSH], 1);
  }
  __syncthreads();
  if (t < NB && hist[t]) atomicAdd(&bcnt[t], hist[t]);
}

__global__ __launch_bounds__(256) void bscan_kernel(
    const int* __restrict__ bcnt, int* __restrict__ bbase, int* __restrict__ bcur, int NB)
{
  __shared__ int ps[256];
  const int t = threadIdx.x;
  int c = (t < NB) ? bcnt[t] : 0;
  ps[t] = c;
  __syncthreads();
  for (int d = 1; d < 256; d <<= 1) {
    int u = (t >= d) ? ps[t - d] : 0;
    __syncthreads();
    ps[t] += u;
    __syncthreads();
  }
  int excl = ps[t] - c;
  if (t <= NB) {
    bbase[t] = excl;
    if (t < NB) bcur[t] = excl;
  }
}

__global__ __launch_bounds__(256) void scatterA_kernel(
    const int* __restrict__ src, const int* __restrict__ dst,
    int* __restrict__ bcur, unsigned* __restrict__ pkbuf,
    int E, int T, int chunk, int NB)
{
  __shared__ int hist[256];
  __shared__ int lbase[256];
  __shared__ int lcur[256];
  const int t = threadIdx.x;
  hist[t] = 0;
  __syncthreads();
  int s0 = blockIdx.x * chunk;
  int s1 = min(s0 + chunk, T);
  for (int i = s0 + t; i < s1; i += 256) {
    int d = (i < E) ? dst[i] : (i - E);
    atomicAdd(&hist[d >> BSH], 1);
  }
  __syncthreads();
  if (t < NB) {
    int h = hist[t];
    lbase[t] = h ? atomicAdd(&bcur[t], h) : 0;
    lcur[t] = 0;
  }
  __syncthreads();
  for (int i = s0 + t; i < s1; i += 256) {
    int d, s;
    if (i < E) { d = dst[i]; s = src[i]; } else { d = s = i - E; }
    int b = d >> BSH;
    int p = lbase[b] + atomicAdd(&lcur[b], 1);
    pkbuf[p] = ((unsigned)(d & BMASK) << 17) | (unsigned)s;
  }
}

__global__ __launch_bounds__(256) void passB_kernel(
    const unsigned* __restrict__ pkbuf, const int* __restrict__ bbase,
    int* __restrict__ offs, int* __restrict__ ssrc, int N, int T, int NBlast)
{
  __shared__ int cnt[512];
  __shared__ int ps[256];
  __shared__ int cur[512];
  const int t = threadIdx.x;
  const int b = blockIdx.x;
  const int bs = bbase[b], be = bbase[b + 1];

  cnt[t] = 0; cnt[t + 256] = 0;
  __syncthreads();
  for (int i = bs + t; i < be; i += 256)
    atomicAdd(&cnt[pkbuf[i] >> 17], 1);
  __syncthreads();

  int a = cnt[2 * t], b2 = cnt[2 * t + 1];
  ps[t] = a + b2;
  __syncthreads();
  for (int d = 1; d < 256; d <<= 1) {
    int u = (t >= d) ? ps[t - d] : 0;
    __syncthreads();
    ps[t] += u;
    __syncthreads();
  }
  int excl = ps[t] - (a + b2);
  cur[2 * t] = excl;
  cur[2 * t + 1] = excl + a;
  __syncthreads();

  const int node0 = b << BSH;
  #pragma unroll
  for (int jj = 0; jj < 2; ++jj) {
    int d = t + jj * 256;
    int node = node0 + d;
    if (node < N) offs[node] = bs + cur[d];
  }
  if (b == NBlast && t == 0) offs[N] = T;
  __syncthreads();

  for (int i = bs + t; i < be; i += 256) {
    unsigned pk = pkbuf[i];
    int d = pk >> 17;
    int p = atomicAdd(&cur[d], 1);
    ssrc[bs + p] = (int)(pk & 0x1FFFFu);
  }
}

// ---------------------------------------------------------------------------
// Layer-1 aggregation (single pass). bf16 gathers; bf16 h_post.
// ---------------------------------------------------------------------------
__global__ __launch_bounds__(256) void agg1_kernel(
    const int* __restrict__ offs, const int* __restrict__ ssrc,
    const float* __restrict__ as1, const float* __restrict__ ad1,
    const unsigned* __restrict__ h1b,
    const float* __restrict__ bias1, const float* __restrict__ gamma,
    const float* __restrict__ beta, const float* __restrict__ mean,
    const float* __restrict__ var,
    const unsigned* __restrict__ identb, unsigned* __restrict__ hpostb, int N)
{
  const int w = threadIdx.x >> 6, l = threadIdx.x & 63;
  const int n = blockIdx.x * 4 + w;
  if (n >= N) return;
  const int h = l >> 3;
  const int c0 = l * 2;
  const float ad = ad1[(size_t)n * 8 + h];
  const int jb = offs[n], je = offs[n + 1];

  float denom = 0.f, a0 = 0.f, a1 = 0.f;

#define EDGE1(SS) { \
    float e = as1[(size_t)(SS) * 8 + h] + ad; \
    e = fmaxf(e, NEG_SLOPE * e); \
    float ex = __expf(e); \
    unsigned u = h1b[(size_t)(SS) * 64 + l]; \
    denom += ex; \
    a0 += ex * bf_lo(u); \
    a1 += ex * bf_hi(u); }

  int j = jb;
  for (; j + 4 <= je; j += 4) {
    int s0 = ssrc[j], s1 = ssrc[j + 1], s2 = ssrc[j + 2], s3 = ssrc[j + 3];
    EDGE1(s0) EDGE1(s1) EDGE1(s2) EDGE1(s3)
  }
  for (; j < je; ++j) { int s = ssrc[j]; EDGE1(s) }
#undef EDGE1

  float inv = 1.f / (denom + 1e-16f);
  unsigned uid = identb[(size_t)n * 64 + l];
  float o0 = a0 * inv + bias1[c0];
  float o1 = a1 * inv + bias1[c0 + 1];
  o0 = (o0 - mean[c0]) * (gamma[c0] * rsqrtf(var[c0] + BN_EPS)) + beta[c0];
  o1 = (o1 - mean[c0 + 1]) * (gamma[c0 + 1] * rsqrtf(var[c0 + 1] + BN_EPS)) + beta[c0 + 1];
  o0 = o0 > 0.f ? o0 : expm1f(o0);
  o1 = o1 > 0.f ? o1 : expm1f(o1);
  o0 += bf_lo(uid); o1 += bf_hi(uid);
  hpostb[(size_t)n * 64 + l] = pack2bf(o0, o1);
}

// ---------------------------------------------------------------------------
// MFMA GEMM2: 128 rows/block, 4 waves x 2 m-frags. Cols 0..39 (3 n-frags,
// padded to 48) + alpha n-frag (cols 0/1 = as2/ad2 via M2ext).
// A = hpostb (already bf16-packed), staged swizzled to LDS.
// ---------------------------------------------------------------------------
__global__ __launch_bounds__(256) void gemm2_kernel(
    const unsigned* __restrict__ hpostb, const float* __restrict__ W2,
    const float* __restrict__ M2ext,
    unsigned* __restrict__ h2b, float* __restrict__ as2, float* __restrict__ ad2, int N)
{
  __shared__ uint4 Asm4[2048];           // 32 KB
  const int t = threadIdx.x;
  const int l = t & 63, wave = t >> 6;
  const int lx = l & 15, ly = l >> 4;
  const int row0 = blockIdx.x * 128;

  // B-frags: W2 cols (3 n-frags) + alpha frag
  short8 b[3][4];
  short8 b4[4];
  {
    const int c = lx;                     // within-frag col
    #pragma unroll
    for (int nf = 0; nf < 3; ++nf) {
      int col = nf * 16 + lx;
      bool v = col < 40;
      const float* bp = W2 + (v ? col : 0);
      #pragma unroll
      for (int kf = 0; kf < 4; ++kf) {
        int k0 = kf * 32 + ly * 8;
        U8 f;
        if (v) {
          f.u.x = pack2bf(bp[(k0 + 0) * 40], bp[(k0 + 1) * 40]);
          f.u.y = pack2bf(bp[(k0 + 2) * 40], bp[(k0 + 3) * 40]);
          f.u.z = pack2bf(bp[(k0 + 4) * 40], bp[(k0 + 5) * 40]);
          f.u.w = pack2bf(bp[(k0 + 6) * 40], bp[(k0 + 7) * 40]);
        } else {
          f.u = make_uint4(0, 0, 0, 0);
        }
        b[nf][kf] = f.s;
      }
    }
    bool va = lx < 2;
    const float* bp = M2ext + (va ? lx : 0);
    #pragma unroll
    for (int kf = 0; kf < 4; ++kf) {
      int k0 = kf * 32 + ly * 8;
      U8 f;
      if (va) {
        f.u.x = pack2bf(bp[(k0 + 0) * 2], bp[(k0 + 1) * 2]);
        f.u.y = pack2bf(bp[(k0 + 2) * 2], bp[(k0 + 3) * 2]);
        f.u.z = pack2bf(bp[(k0 + 4) * 2], bp[(k0 + 5) * 2]);
        f.u.w = pack2bf(bp[(k0 + 6) * 2], bp[(k0 + 7) * 2]);
      } else {
        f.u = make_uint4(0, 0, 0, 0);
      }
      b4[kf] = f.s;
    }
    (void)c;
  }

  // stage A tile (bf16 already): 2 threads/row, 8 uint4 each
  {
    int rl = t >> 1;
    int half = t & 1;
    int r = row0 + rl;
    const unsigned* xp = hpostb + (size_t)r * 64 + half * 32;
    #pragma unroll
    for (int i = 0; i < 8; ++i) {
      uint4 u = make_uint4(0, 0, 0, 0);
      if (r < N) u = *(const uint4*)(xp + i * 4);
      int woff = (rl * 256 + half * 128 + i * 16) ^ ((rl & 7) << 4);
      *(uint4*)((char*)Asm4 + woff) = u;
    }
  }
  __syncthreads();

  #pragma unroll
  for (int i = 0; i < 2; ++i) {
    int mf = wave * 2 + i;
    short8 a[4];
    int rowl = mf * 16 + lx;
    #pragma unroll
    for (int kf = 0; kf < 4; ++kf)
      a[kf] = *(short8*)((char*)Asm4 + ((rowl * 256 + kf * 64 + ly * 16) ^ ((lx & 7) << 4)));

    int rbase = row0 + mf * 16 + ly * 4;

    #pragma unroll
    for (int nf = 0; nf < 3; ++nf) {
      f32x4 acc = {0.f, 0.f, 0.f, 0.f};
      #pragma unroll
      for (int kf = 0; kf < 4; ++kf)
        acc = __builtin_amdgcn_mfma_f32_16x16x32_bf16(a[kf], b[nf][kf], acc, 0, 0, 0);
      int c = nf * 16 + lx;
      #pragma unroll
      for (int reg = 0; reg < 4; ++reg) {
        float v = acc[reg];
        float vp = __shfl_xor(v, 1, 64);
        int r = rbase + reg;
        if (r < N && c < 40 && !(lx & 1))
          h2b[(size_t)r * 20 + (c >> 1)] = pack2bf(v, vp);
      }
    }
    {
      f32x4 acc = {0.f, 0.f, 0.f, 0.f};
      #pragma unroll
      for (int kf = 0; kf < 4; ++kf)
        acc = __builtin_amdgcn_mfma_f32_16x16x32_bf16(a[kf], b4[kf], acc, 0, 0, 0);
      #pragma unroll
      for (int reg = 0; reg < 4; ++reg) {
        int r = rbase + reg;
        if (r < N) {
          if (lx == 0) as2[r] = acc[reg];
          else if (lx == 1) ad2[r] = acc[reg];
        }
      }
    }
  }
}

// ---------------------------------------------------------------------------
// Layer-2 aggregation + bias2 + fused log_softmax.
// ---------------------------------------------------------------------------
__global__ __launch_bounds__(256) void agg2_kernel(
    const int* __restrict__ offs, const int* __restrict__ ssrc,
    const float* __restrict__ as2, const float* __restrict__ ad2,
    const unsigned* __restrict__ h2b, const float* __restrict__ bias2,
    float* __restrict__ outp, int N)
{
  const int w = threadIdx.x >> 6, l = threadIdx.x & 63;
  const int n = blockIdx.x * 4 + w;
  if (n >= N) return;
  const int lc = l < 20 ? l : 0;
  const float ad = ad2[n];
  const int jb = offs[n], je = offs[n + 1];

  float denom = 0.f, a0 = 0.f, a1 = 0.f;

#define EDGE2(SS) { \
    float e = as2[SS] + ad; \
    e = fmaxf(e, NEG_SLOPE * e); \
    float ex = __expf(e); \
    unsigned u = h2b[(size_t)(SS) * 20 + lc]; \
    denom += ex; \
    a0 += ex * bf_lo(u); \
    a1 += ex * bf_hi(u); }

  int j = jb;
  for (; j + 4 <= je; j += 4) {
    int s0 = ssrc[j], s1 = ssrc[j + 1], s2 = ssrc[j + 2], s3 = ssrc[j + 3];
    EDGE2(s0) EDGE2(s1) EDGE2(s2) EDGE2(s3)
  }
  for (; j < je; ++j) { int s = ssrc[j]; EDGE2(s) }
#undef EDGE2

  float inv = 1.f / (denom + 1e-16f);
  float o0 = a0 * inv + bias2[2 * lc];
  float o1 = a1 * inv + bias2[2 * lc + 1];

  float mx = wave_max64(l < 20 ? fmaxf(o0, o1) : -3.4e38f);
  float se = wave_sum64(l < 20 ? __expf(o0 - mx) + __expf(o1 - mx) : 0.f);
  float ls = logf(se);
  if (l < 20)
    *(float2*)&outp[(size_t)n * 40 + 2 * l] = make_float2(o0 - mx - ls, o1 - mx - ls);
}

// ---------------------------------------------------------------------------
extern "C" void kernel_launch(void* const* d_in, const int* in_sizes, int n_in,
                              void* d_out, int out_size, void* d_ws, size_t ws_size,
                              hipStream_t stream)
{
  const float* x        = (const float*)d_in[0];
  const int*   ei       = (const int*)d_in[1];
  const float* W1       = (const float*)d_in[2];
  const float* att_src1 = (const float*)d_in[3];
  const float* att_dst1 = (const float*)d_in[4];
  const float* bias1    = (const float*)d_in[5];
  const float* bn_gamma = (const float*)d_in[6];
  const float* bn_beta  = (const float*)d_in[7];
  const float* bn_mean  = (const float*)d_in[8];
  const float* bn_var   = (const float*)d_in[9];
  const float* W2       = (const float*)d_in[10];
  const float* att_src2 = (const float*)d_in[11];
  const float* att_dst2 = (const float*)d_in[12];
  const float* bias2    = (const float*)d_in[13];
  const float* W_skip   = (const float*)d_in[14];
  const float* b_skip   = (const float*)d_in[15];

  const int N = in_sizes[0] / 128;
  const int E = in_sizes[1] / 2;
  const int T = E + N;
  const int NB = (N + BMASK) >> BSH;

  char* p = (char*)d_ws;
  auto alloc = [&](size_t bytes) { char* q = p; p += (bytes + 255) & ~255ull; return q; };
  unsigned* h1b    = (unsigned*)alloc((size_t)N * 64 * 4);   // bf16 [N][128]
  unsigned* hpostb = (unsigned*)alloc((size_t)N * 64 * 4);
  unsigned* identb = (unsigned*)alloc((size_t)N * 64 * 4);
  float* as1     = (float*)alloc((size_t)N * 8 * 4);
  float* ad1     = (float*)alloc((size_t)N * 8 * 4);
  float* Mext    = (float*)alloc(128 * 16 * 4);
  float* M2ext   = (float*)alloc(128 * 2 * 4);
  int*   offs    = (int*)alloc((size_t)(N + 1) * 4);
  unsigned* pkbuf= (unsigned*)alloc((size_t)T * 4);
  int*   ssrc    = (int*)alloc((size_t)T * 4);
  int*   bcnt    = (int*)alloc((size_t)(NB + 1) * 4);
  int*   bbase   = (int*)alloc((size_t)(NB + 1) * 4);
  int*   bcur    = (int*)alloc((size_t)NB * 4);
  unsigned* h2b = h1b;
  float* as2 = as1;
  float* ad2 = ad1;

  const int* ei_src = ei;
  const int* ei_dst = ei + E;

  hipMemsetAsync(bcnt, 0, (size_t)(NB + 1) * 4, stream);

  prep_kernel<<<1, 128, 0, stream>>>(W1, att_src1, att_dst1, Mext,
                                     W2, att_src2, att_dst2, M2ext);
  gemm1_kernel<<<(N + 127) / 128, 256, 0, stream>>>(
      x, W1, W_skip, b_skip, Mext,
      (unsigned short*)h1b, (unsigned short*)identb, as1, ad1, N);

  const int NBLK_A = 512;
  const int chunk = (T + NBLK_A - 1) / NBLK_A;
  hist_kernel<<<NBLK_A, 256, 0, stream>>>(ei_src, ei_dst, bcnt, E, T, chunk, NB);
  bscan_kernel<<<1, 256, 0, stream>>>(bcnt, bbase, bcur, NB);
  scatterA_kernel<<<NBLK_A, 256, 0, stream>>>(ei_src, ei_dst, bcur, pkbuf, E, T, chunk, NB);
  passB_kernel<<<NB, 256, 0, stream>>>(pkbuf, bbase, offs, ssrc, N, T, NB - 1);

  agg1_kernel<<<(N + 3) / 4, 256, 0, stream>>>(offs, ssrc, as1, ad1, h1b,
                                               bias1, bn_gamma, bn_beta, bn_mean, bn_var,
                                               identb, hpostb, N);
  gemm2_kernel<<<(N + 127) / 128, 256, 0, stream>>>(hpostb, W2, M2ext,
                                                    h2b, as2, ad2, N);
  agg2_kernel<<<(N + 3) / 4, 256, 0, stream>>>(offs, ssrc, as2, ad2, h2b, bias2,
                                               (float*)d_out, N);
}